// Round 1
// baseline (730.698 us; speedup 1.0000x reference)
//
#include <hip/hip_runtime.h>
#include <math.h>

// Problem constants
#define B_   2
#define C_   256
#define H_   56
#define W_   56
#define NQ_  3136
#define NH_  8
#define HD_  32
#define FFN_ 1024
#define EPSV 1e-5f
#define SCALV 0.17677669529663687f   // 32^-0.5

// ---------------------------------------------------------------------------
// 1) Transpose src (B,C,HW) -> X (B,HW,C)
__global__ __launch_bounds__(256) void k_transpose(const float* __restrict__ src, float* __restrict__ X) {
  __shared__ float tile[32][33];
  int b = blockIdx.z;
  int hw0 = blockIdx.x * 32, c0 = blockIdx.y * 32;
  int tx = threadIdx.x, ty = threadIdx.y;
  for (int i = ty; i < 32; i += 8)
    tile[i][tx] = src[((size_t)(b * 256 + c0 + i)) * 3136 + hw0 + tx];
  __syncthreads();
  for (int i = ty; i < 32; i += 8)
    X[((size_t)(b * 3136 + hw0 + i)) * 256 + c0 + tx] = tile[tx][i];
}

// 2) Mean over h (->MH: B,W,C) and over w (->MW: B,H,C), read from src layout
__global__ void k_means(const float* __restrict__ src, float* __restrict__ MH, float* __restrict__ MW) {
  int c = blockIdx.x, b = blockIdx.y, t = threadIdx.x;
  if (t >= 56) return;
  const float* p = src + ((size_t)(b * 256 + c)) * 3136;
  float sH = 0.f, sW = 0.f;
  for (int i = 0; i < 56; ++i) {
    sH += p[i * 56 + t];
    sW += p[t * 56 + i];
  }
  MH[((size_t)(b * 56 + t)) * 256 + c] = sH * (1.f / 56.f);
  MW[((size_t)(b * 56 + t)) * 256 + c] = sW * (1.f / 56.f);
}

// 3) Small projections: PRW = per@Wqr^T, PCW = pec@Wqc^T,
//    KR = (MH+per)@Wkr^T + bkr, KC = (MW+pec)@Wkc^T + bkc.  112 rows each.
__global__ __launch_bounds__(256) void k_smallproj(
    const float* __restrict__ per, const float* __restrict__ pec,
    const float* __restrict__ mh, const float* __restrict__ mw,
    const float* __restrict__ wqr, const float* __restrict__ wqc,
    const float* __restrict__ wkr, const float* __restrict__ wkc,
    const float* __restrict__ bkr, const float* __restrict__ bkc,
    float* __restrict__ PRW, float* __restrict__ PCW,
    float* __restrict__ KR, float* __restrict__ KC) {
  __shared__ __align__(16) float inb[256];
  int s = blockIdx.x / 112;
  int r = blockIdx.x % 112;
  int j = threadIdx.x;
  const float* i0; const float* i1 = nullptr; const float* W;
  const float* bias = nullptr; float* out;
  if (s == 0)      { i0 = per; W = wqr; out = PRW; }
  else if (s == 1) { i0 = pec; W = wqc; out = PCW; }
  else if (s == 2) { i0 = per; i1 = mh; W = wkr; bias = bkr; out = KR; }
  else             { i0 = pec; i1 = mw; W = wkc; bias = bkc; out = KC; }
  float v = i0[(size_t)r * 256 + j];
  if (i1) v += i1[(size_t)r * 256 + j];
  inb[j] = v;
  __syncthreads();
  const float* wrow = W + (size_t)j * 256;
  float acc = 0.f;
  #pragma unroll
  for (int c4 = 0; c4 < 64; ++c4) {
    float4 iv = *(const float4*)(&inb[c4 * 4]);
    float4 wv = *(const float4*)(wrow + c4 * 4);
    acc += iv.x * wv.x + iv.y * wv.y + iv.z * wv.z + iv.w * wv.w;
  }
  if (bias) acc += bias[j];
  out[(size_t)r * 256 + j] = acc;
}

// 4) Fused projection GEMM: X(6272,256) @ [Wqr|Wqc|Wv]^T -> QR,QC,V with epilogues
__global__ __launch_bounds__(256) void k_projgemm(
    const float* __restrict__ X,
    const float* __restrict__ Wqr, const float* __restrict__ Wqc, const float* __restrict__ Wv,
    const float* __restrict__ bqr, const float* __restrict__ bqc, const float* __restrict__ bv,
    const float* __restrict__ PRW, const float* __restrict__ PCW,
    float* __restrict__ QR, float* __restrict__ QC, float* __restrict__ V) {
  __shared__ __align__(16) float As[32][68];
  __shared__ __align__(16) float Bs[32][68];
  int tx = threadIdx.x, ty = threadIdx.y;
  int tid = ty * 16 + tx;
  int m0 = blockIdx.x * 64;
  int j0 = blockIdx.y * 64;
  int s  = j0 >> 8;          // 0: q_row, 1: q_col, 2: v
  int jb = j0 & 255;
  const float* Wp = (s == 0) ? Wqr : (s == 1) ? Wqc : Wv;
  float acc[4][4] = {};
  for (int k0 = 0; k0 < 256; k0 += 32) {
    for (int l = tid; l < 512; l += 256) {
      int mm = l >> 3;
      int kq = (l & 7) << 2;
      float4 a = *(const float4*)(X + (size_t)(m0 + mm) * 256 + k0 + kq);
      As[kq + 0][mm] = a.x; As[kq + 1][mm] = a.y; As[kq + 2][mm] = a.z; As[kq + 3][mm] = a.w;
      float4 bq = *(const float4*)(Wp + (size_t)(jb + mm) * 256 + k0 + kq);
      Bs[kq + 0][mm] = bq.x; Bs[kq + 1][mm] = bq.y; Bs[kq + 2][mm] = bq.z; Bs[kq + 3][mm] = bq.w;
    }
    __syncthreads();
    #pragma unroll
    for (int kk = 0; kk < 32; ++kk) {
      float4 av = *(const float4*)(&As[kk][ty * 4]);
      float4 bv4 = *(const float4*)(&Bs[kk][tx * 4]);
      float aa[4] = {av.x, av.y, av.z, av.w};
      float bb[4] = {bv4.x, bv4.y, bv4.z, bv4.w};
      #pragma unroll
      for (int i = 0; i < 4; ++i)
        #pragma unroll
        for (int j = 0; j < 4; ++j) acc[i][j] += aa[i] * bb[j];
    }
    __syncthreads();
  }
  int jj = jb + tx * 4;
  #pragma unroll
  for (int i = 0; i < 4; ++i) {
    int M = m0 + ty * 4 + i;
    int b = M / 3136;
    int q = M % 3136;
    float4 r = {acc[i][0], acc[i][1], acc[i][2], acc[i][3]};
    if (s == 0) {
      int w = q % 56;
      const float* pr = PRW + ((size_t)(b * 56 + w)) * 256 + jj;
      r.x = (r.x + pr[0] + bqr[jj + 0]) * SCALV;
      r.y = (r.y + pr[1] + bqr[jj + 1]) * SCALV;
      r.z = (r.z + pr[2] + bqr[jj + 2]) * SCALV;
      r.w = (r.w + pr[3] + bqr[jj + 3]) * SCALV;
      *(float4*)(QR + (size_t)M * 256 + jj) = r;
    } else if (s == 1) {
      int h = q / 56;
      const float* pc = PCW + ((size_t)(b * 56 + h)) * 256 + jj;
      r.x = (r.x + pc[0] + bqc[jj + 0]) * SCALV;
      r.y = (r.y + pc[1] + bqc[jj + 1]) * SCALV;
      r.z = (r.z + pc[2] + bqc[jj + 2]) * SCALV;
      r.w = (r.w + pc[3] + bqc[jj + 3]) * SCALV;
      *(float4*)(QC + (size_t)M * 256 + jj) = r;
    } else {
      r.x += bv[jj + 0]; r.y += bv[jj + 1]; r.z += bv[jj + 2]; r.w += bv[jj + 3];
      *(float4*)(V + (size_t)M * 256 + jj) = r;
    }
  }
}

// 5) Scores + softmax.  One wave per (q, head, row|col). K tile staged in LDS.
__global__ __launch_bounds__(256) void k_scores(
    const float* __restrict__ QR, const float* __restrict__ QC,
    const float* __restrict__ KR, const float* __restrict__ KC,
    const unsigned char* __restrict__ pm,
    float* __restrict__ AWR, float* __restrict__ AWC) {
  __shared__ float Ks[56][33];
  int tid = threadIdx.x;
  int n = blockIdx.y & 7;
  int isCol = blockIdx.y >> 3;
  int b = blockIdx.z;
  const float* Kg = isCol ? KC : KR;
  for (int l = tid; l < 56 * 32; l += 256) {
    int w = l >> 5, d = l & 31;
    Ks[w][d] = Kg[((size_t)(b * 56 + w) << 8) + (n << 5) + d];
  }
  __syncthreads();
  int wave = tid >> 6, ln = tid & 63;
  int q = blockIdx.x * 4 + wave;
  const float* Qg = (isCol ? QC : QR) + ((size_t)(b * 3136 + q) << 8) + (n << 5);
  float sc = -INFINITY;
  if (ln < 56) {
    float s = 0.f;
    #pragma unroll
    for (int d4 = 0; d4 < 8; ++d4) {
      float4 qv = *(const float4*)(Qg + d4 * 4);
      s += qv.x * Ks[ln][d4 * 4 + 0] + qv.y * Ks[ln][d4 * 4 + 1]
         + qv.z * Ks[ln][d4 * 4 + 2] + qv.w * Ks[ln][d4 * 4 + 3];
    }
    bool msk = isCol ? (pm[(size_t)b * 3136 + ln * 56] != 0)
                     : (pm[(size_t)b * 3136 + ln] != 0);
    if (msk) s = -3.402823466e38f;
    sc = s;
  }
  float mx = sc;
  for (int o = 32; o; o >>= 1) mx = fmaxf(mx, __shfl_xor(mx, o));
  float e = (ln < 56) ? __expf(sc - mx) : 0.f;
  float ss = e;
  for (int o = 32; o; o >>= 1) ss += __shfl_xor(ss, o);
  float aw = e / ss;
  if (ln < 56) {
    float* AW = isCol ? AWC : AWR;
    AW[((size_t)(b * 8 + n) * 3136 + q) * 56 + ln] = aw;
  }
}

// 6) Attention recombination: ATT[b,q,n,d] = sum_h Ac[q,h] * sum_w Ar[q,w] * V[h,w,n,d]
__global__ __launch_bounds__(256) void k_attn(
    const float* __restrict__ AWRg, const float* __restrict__ AWCg,
    const float* __restrict__ V, float* __restrict__ ATT) {
  __shared__ float Ar[32][57];
  __shared__ float Ac[32][57];
  __shared__ __align__(16) float Vh[56][36];
  int tid = threadIdx.x;
  int q0 = blockIdx.x * 32;
  int n = blockIdx.y;
  int b = blockIdx.z;
  size_t awbase = ((size_t)(b * 8 + n) * 3136 + q0) * 56;
  for (int l = tid; l < 32 * 56; l += 256) {
    int q = l / 56, w = l % 56;
    Ar[q][w] = AWRg[awbase + (size_t)q * 56 + w];
    Ac[q][w] = AWCg[awbase + (size_t)q * 56 + w];
  }
  int q = tid >> 3;
  int d0 = (tid & 7) << 2;
  float4 acc = {0.f, 0.f, 0.f, 0.f};
  size_t vbase = (((size_t)b * 3136) << 8) + (n << 5);
  for (int h = 0; h < 56; ++h) {
    __syncthreads();   // protect Vh (prev iter) / Ar,Ac (first iter)
    for (int l = tid; l < 56 * 32; l += 256) {
      int w = l >> 5, d = l & 31;
      Vh[w][d] = V[vbase + ((size_t)(h * 56 + w) << 8) + d];
    }
    __syncthreads();
    float4 p = {0.f, 0.f, 0.f, 0.f};
    #pragma unroll 7
    for (int w = 0; w < 56; ++w) {
      float a = Ar[q][w];
      float4 vv = *(const float4*)(&Vh[w][d0]);
      p.x += a * vv.x; p.y += a * vv.y; p.z += a * vv.z; p.w += a * vv.w;
    }
    float acl = Ac[q][h];
    acc.x += acl * p.x; acc.y += acl * p.y; acc.z += acl * p.z; acc.w += acl * p.w;
  }
  *(float4*)(ATT + (((size_t)(b * 3136 + q0 + q)) << 8) + (n << 5) + d0) = acc;
}

// 7) Generic 64x64-tile GEMM: Out(M,N) = A(M,K) @ W(N,K)^T + bias, EPI=1 -> relu
template<int EPI>
__global__ __launch_bounds__(256) void k_gemm64(
    const float* __restrict__ A, const float* __restrict__ Wt,
    const float* __restrict__ bias, float* __restrict__ Out, int K, int N) {
  __shared__ __align__(16) float As[32][68];
  __shared__ __align__(16) float Bs[32][68];
  int tx = threadIdx.x, ty = threadIdx.y;
  int tid = ty * 16 + tx;
  int m0 = blockIdx.x * 64;
  int j0 = blockIdx.y * 64;
  float acc[4][4] = {};
  for (int k0 = 0; k0 < K; k0 += 32) {
    for (int l = tid; l < 512; l += 256) {
      int mm = l >> 3;
      int kq = (l & 7) << 2;
      float4 a = *(const float4*)(A + (size_t)(m0 + mm) * K + k0 + kq);
      As[kq + 0][mm] = a.x; As[kq + 1][mm] = a.y; As[kq + 2][mm] = a.z; As[kq + 3][mm] = a.w;
      float4 bq = *(const float4*)(Wt + (size_t)(j0 + mm) * K + k0 + kq);
      Bs[kq + 0][mm] = bq.x; Bs[kq + 1][mm] = bq.y; Bs[kq + 2][mm] = bq.z; Bs[kq + 3][mm] = bq.w;
    }
    __syncthreads();
    #pragma unroll
    for (int kk = 0; kk < 32; ++kk) {
      float4 av = *(const float4*)(&As[kk][ty * 4]);
      float4 bv4 = *(const float4*)(&Bs[kk][tx * 4]);
      float aa[4] = {av.x, av.y, av.z, av.w};
      float bb[4] = {bv4.x, bv4.y, bv4.z, bv4.w};
      #pragma unroll
      for (int i = 0; i < 4; ++i)
        #pragma unroll
        for (int j = 0; j < 4; ++j) acc[i][j] += aa[i] * bb[j];
    }
    __syncthreads();
  }
  #pragma unroll
  for (int i = 0; i < 4; ++i) {
    int M = m0 + ty * 4 + i;
    int j = j0 + tx * 4;
    float4 r;
    r.x = acc[i][0] + bias[j + 0];
    r.y = acc[i][1] + bias[j + 1];
    r.z = acc[i][2] + bias[j + 2];
    r.w = acc[i][3] + bias[j + 3];
    if (EPI == 1) {
      r.x = fmaxf(r.x, 0.f); r.y = fmaxf(r.y, 0.f);
      r.z = fmaxf(r.z, 0.f); r.w = fmaxf(r.w, 0.f);
    }
    *(float4*)(Out + (size_t)M * N + j) = r;
  }
}

// 8) LN1: XN1 = LayerNorm(Y + X), one wave per row
__global__ __launch_bounds__(256) void k_ln1(
    const float* __restrict__ Y, const float* __restrict__ X,
    const float* __restrict__ g, const float* __restrict__ bb,
    float* __restrict__ XN1) {
  int tid = threadIdx.x;
  int row = blockIdx.x * 4 + (tid >> 6);
  int ln = tid & 63;
  size_t base = (size_t)row * 256 + ln * 4;
  float4 y = *(const float4*)(Y + base);
  float4 x = *(const float4*)(X + base);
  float v0 = y.x + x.x, v1 = y.y + x.y, v2 = y.z + x.z, v3 = y.w + x.w;
  float s = v0 + v1 + v2 + v3;
  float s2 = v0 * v0 + v1 * v1 + v2 * v2 + v3 * v3;
  for (int o = 32; o; o >>= 1) { s += __shfl_xor(s, o); s2 += __shfl_xor(s2, o); }
  float m = s * (1.f / 256.f);
  float inv = rsqrtf(fmaxf(s2 * (1.f / 256.f) - m * m, 0.f) + EPSV);
  float4 gg = *(const float4*)(g + ln * 4);
  float4 bv = *(const float4*)(bb + ln * 4);
  float4 o4;
  o4.x = (v0 - m) * inv * gg.x + bv.x;
  o4.y = (v1 - m) * inv * gg.y + bv.y;
  o4.z = (v2 - m) * inv * gg.z + bv.z;
  o4.w = (v3 - m) * inv * gg.w + bv.w;
  *(float4*)(XN1 + base) = o4;
}

// 9) LN2 + transposed store to (B,C,H,W)
__global__ __launch_bounds__(256) void k_ln2t(
    const float* __restrict__ Y2, const float* __restrict__ XN1,
    const float* __restrict__ g, const float* __restrict__ bb,
    float* __restrict__ out) {
  __shared__ float VL[16][257];
  int tid = threadIdx.x;
  int r0 = blockIdx.x * 16;
  for (int l = tid; l < 16 * 256; l += 256) {
    int r = l >> 8, c = l & 255;
    VL[r][c] = Y2[(size_t)(r0 + r) * 256 + c] + XN1[(size_t)(r0 + r) * 256 + c];
  }
  __syncthreads();
  int wv = tid >> 6, ln = tid & 63;
  for (int rr = wv; rr < 16; rr += 4) {
    float s = 0.f, s2 = 0.f;
    float vv[4];
    #pragma unroll
    for (int i = 0; i < 4; ++i) {
      float v = VL[rr][ln * 4 + i];
      vv[i] = v; s += v; s2 += v * v;
    }
    for (int o = 32; o; o >>= 1) { s += __shfl_xor(s, o); s2 += __shfl_xor(s2, o); }
    float m = s * (1.f / 256.f);
    float inv = rsqrtf(fmaxf(s2 * (1.f / 256.f) - m * m, 0.f) + EPSV);
    #pragma unroll
    for (int i = 0; i < 4; ++i) {
      int c = ln * 4 + i;
      VL[rr][c] = (vv[i] - m) * inv * g[c] + bb[c];
    }
  }
  __syncthreads();
  int b = r0 / 3136;
  int hw0 = r0 % 3136;
  int r = tid & 15, cg = tid >> 4;
  for (int it = 0; it < 16; ++it) {
    int c = it * 16 + cg;
    out[(size_t)(b * 256 + c) * 3136 + hw0 + r] = VL[r][c];
  }
}

// ---------------------------------------------------------------------------
extern "C" void kernel_launch(void* const* d_in, const int* in_sizes, int n_in,
                              void* d_out, int out_size, void* d_ws, size_t ws_size,
                              hipStream_t stream) {
  const float* src = (const float*)d_in[0];
  const unsigned char* pmask = (const unsigned char*)d_in[1];
  const float* per = (const float*)d_in[2];
  const float* pec = (const float*)d_in[3];
  const float* wqr = (const float*)d_in[4];
  const float* bqr = (const float*)d_in[5];
  const float* wqc = (const float*)d_in[6];
  const float* bqc = (const float*)d_in[7];
  const float* wkr = (const float*)d_in[8];
  const float* bkr = (const float*)d_in[9];
  const float* wkc = (const float*)d_in[10];
  const float* bkc = (const float*)d_in[11];
  const float* wv  = (const float*)d_in[12];
  const float* bv  = (const float*)d_in[13];
  const float* wo  = (const float*)d_in[14];
  const float* bo  = (const float*)d_in[15];
  const float* n1g = (const float*)d_in[16];
  const float* n1b = (const float*)d_in[17];
  const float* l1w = (const float*)d_in[18];
  const float* l1b = (const float*)d_in[19];
  const float* l2w = (const float*)d_in[20];
  const float* l2b = (const float*)d_in[21];
  const float* n2g = (const float*)d_in[22];
  const float* n2b = (const float*)d_in[23];

  float* ws  = (float*)d_ws;
  float* X   = ws;
  float* QR  = X   + 1605632;
  float* QC  = QR  + 1605632;
  float* V   = QC  + 1605632;
  float* ATT = V   + 1605632;
  float* AWR = ATT + 1605632;
  float* AWC = AWR + 2809856;
  float* FF  = AWC + 2809856;
  float* MH  = FF  + 6422528;
  float* MW  = MH  + 28672;
  float* PRW = MW  + 28672;
  float* PCW = PRW + 28672;
  float* KR  = PCW + 28672;
  float* KC  = KR  + 28672;
  float* Y   = QR;    // reuse (QR dead after scores)
  float* XN1 = QC;    // reuse (QC dead after scores)
  float* Y2  = ATT;   // reuse (ATT dead after out-proj)
  float* out = (float*)d_out;

  k_transpose<<<dim3(98, 8, 2), dim3(32, 8), 0, stream>>>(src, X);
  k_means<<<dim3(256, 2), 64, 0, stream>>>(src, MH, MW);
  k_smallproj<<<448, 256, 0, stream>>>(per, pec, MH, MW, wqr, wqc, wkr, wkc,
                                       bkr, bkc, PRW, PCW, KR, KC);
  k_projgemm<<<dim3(98, 12), dim3(16, 16), 0, stream>>>(X, wqr, wqc, wv, bqr, bqc, bv,
                                                        PRW, PCW, QR, QC, V);
  k_scores<<<dim3(784, 16, 2), 256, 0, stream>>>(QR, QC, KR, KC, pmask, AWR, AWC);
  k_attn<<<dim3(98, 8, 2), 256, 0, stream>>>(AWR, AWC, V, ATT);
  k_gemm64<0><<<dim3(98, 4), dim3(16, 16), 0, stream>>>(ATT, wo, bo, Y, 256, 256);
  k_ln1<<<1568, 256, 0, stream>>>(Y, X, n1g, n1b, XN1);
  k_gemm64<1><<<dim3(98, 16), dim3(16, 16), 0, stream>>>(XN1, l1w, l1b, FF, 256, 1024);
  k_gemm64<0><<<dim3(98, 4), dim3(16, 16), 0, stream>>>(FF, l2w, l2b, Y2, 1024, 256);
  k_ln2t<<<392, 256, 0, stream>>>(Y2, XN1, n2g, n2b, out);
}

// Round 2
// 308.537 us; speedup vs baseline: 2.3683x; 2.3683x over previous
//
#include <hip/hip_runtime.h>
#include <math.h>

#define EPSV 1e-5f
#define SCALV 0.17677669529663687f   // 32^-0.5

typedef __attribute__((ext_vector_type(8))) short s16x8;
typedef __attribute__((ext_vector_type(8))) __bf16 bf8_t;
typedef __attribute__((ext_vector_type(4))) float f32x4;

__device__ inline unsigned short f2bfu(float f) {
  union { float f; unsigned u; } v; v.f = f;
  return (unsigned short)((v.u + 0x7FFFu + ((v.u >> 16) & 1u)) >> 16);
}

__device__ inline f32x4 mfma16(s16x8 a, s16x8 b, f32x4 c) {
  return __builtin_amdgcn_mfma_f32_16x16x32_bf16(
      __builtin_bit_cast(bf8_t, a), __builtin_bit_cast(bf8_t, b), c, 0, 0, 0);
}

// ---------------------------------------------------------------------------
// 1) Transpose src (B,C,HW) -> X (B,HW,C) fp32 + Xb bf16
__global__ __launch_bounds__(256) void k_transpose(const float* __restrict__ src,
                                                   float* __restrict__ X,
                                                   short* __restrict__ Xb) {
  __shared__ float tile[32][33];
  int b = blockIdx.z;
  int hw0 = blockIdx.x * 32, c0 = blockIdx.y * 32;
  int tx = threadIdx.x, ty = threadIdx.y;
  for (int i = ty; i < 32; i += 8)
    tile[i][tx] = src[((size_t)(b * 256 + c0 + i)) * 3136 + hw0 + tx];
  __syncthreads();
  for (int i = ty; i < 32; i += 8) {
    float v = tile[tx][i];
    size_t idx = ((size_t)(b * 3136 + hw0 + i)) * 256 + c0 + tx;
    X[idx] = v;
    Xb[idx] = (short)f2bfu(v);
  }
}

// 2) Mean over h (->MH: B,W,C) and over w (->MW: B,H,C)
__global__ void k_means(const float* __restrict__ src, float* __restrict__ MH, float* __restrict__ MW) {
  int c = blockIdx.x, b = blockIdx.y, t = threadIdx.x;
  if (t >= 56) return;
  const float* p = src + ((size_t)(b * 256 + c)) * 3136;
  float sH = 0.f, sW = 0.f;
  for (int i = 0; i < 56; ++i) {
    sH += p[i * 56 + t];
    sW += p[t * 56 + i];
  }
  MH[((size_t)(b * 56 + t)) * 256 + c] = sH * (1.f / 56.f);
  MW[((size_t)(b * 56 + t)) * 256 + c] = sW * (1.f / 56.f);
}

// 3) Small projections (112 rows each)
__global__ __launch_bounds__(256) void k_smallproj(
    const float* __restrict__ per, const float* __restrict__ pec,
    const float* __restrict__ mh, const float* __restrict__ mw,
    const float* __restrict__ wqr, const float* __restrict__ wqc,
    const float* __restrict__ wkr, const float* __restrict__ wkc,
    const float* __restrict__ bkr, const float* __restrict__ bkc,
    float* __restrict__ PRW, float* __restrict__ PCW,
    float* __restrict__ KR, float* __restrict__ KC) {
  __shared__ __align__(16) float inb[256];
  int s = blockIdx.x / 112;
  int r = blockIdx.x % 112;
  int j = threadIdx.x;
  const float* i0; const float* i1 = nullptr; const float* W;
  const float* bias = nullptr; float* out;
  if (s == 0)      { i0 = per; W = wqr; out = PRW; }
  else if (s == 1) { i0 = pec; W = wqc; out = PCW; }
  else if (s == 2) { i0 = per; i1 = mh; W = wkr; bias = bkr; out = KR; }
  else             { i0 = pec; i1 = mw; W = wkc; bias = bkc; out = KC; }
  float v = i0[(size_t)r * 256 + j];
  if (i1) v += i1[(size_t)r * 256 + j];
  inb[j] = v;
  __syncthreads();
  const float* wrow = W + (size_t)j * 256;
  float acc = 0.f;
  #pragma unroll
  for (int c4 = 0; c4 < 64; ++c4) {
    float4 iv = *(const float4*)(&inb[c4 * 4]);
    float4 wv = *(const float4*)(wrow + c4 * 4);
    acc += iv.x * wv.x + iv.y * wv.y + iv.z * wv.z + iv.w * wv.w;
  }
  if (bias) acc += bias[j];
  out[(size_t)r * 256 + j] = acc;
}

// 3b) Pack weights to bf16
__global__ __launch_bounds__(256) void k_pack(
    const float* __restrict__ wqr, const float* __restrict__ wqc, const float* __restrict__ wv,
    const float* __restrict__ wo, const float* __restrict__ l1w, const float* __restrict__ l2w,
    short* __restrict__ Wcat, short* __restrict__ wob,
    short* __restrict__ l1b, short* __restrict__ l2b) {
  int seg = blockIdx.y;
  int e = (blockIdx.x * 256 + threadIdx.x) * 4;
  int cnt = (seg == 0) ? 196608 : (seg == 1) ? 65536 : 262144;
  if (e >= cnt) return;
  const float* sp;
  short* dp;
  if (seg == 0) {
    dp = Wcat + e;
    sp = (e < 65536) ? wqr + e : (e < 131072) ? wqc + (e - 65536) : wv + (e - 131072);
  } else if (seg == 1) { dp = wob + e; sp = wo + e; }
  else if (seg == 2)   { dp = l1b + e; sp = l1w + e; }
  else                 { dp = l2b + e; sp = l2w + e; }
  float4 v = *(const float4*)sp;
  uint2 p;
  p.x = (unsigned)f2bfu(v.x) | ((unsigned)f2bfu(v.y) << 16);
  p.y = (unsigned)f2bfu(v.z) | ((unsigned)f2bfu(v.w) << 16);
  *(uint2*)dp = p;
}

// 4) Fused projection MFMA GEMM: Xb(6272,256) @ Wcat(768,256)^T
//    epilogues: j<256: QR fp32 (+PRW+bqr)*scal ; <512: QC ; >=512: Vt bf16 transposed
__global__ __launch_bounds__(256) void k_projmfma(
    const short* __restrict__ A, const short* __restrict__ W,
    const float* __restrict__ bqr, const float* __restrict__ bqc, const float* __restrict__ bv,
    const float* __restrict__ PRW, const float* __restrict__ PCW,
    float* __restrict__ QR, float* __restrict__ QC, short* __restrict__ Vt) {
  __shared__ __align__(16) short As[2560];
  __shared__ __align__(16) short Bs[2560];
  int tid = threadIdx.x;
  int m0 = blockIdx.x * 64, n0 = blockIdx.y * 64;
  int wid = tid >> 6, lane = tid & 63;
  int ln15 = lane & 15, slot = lane >> 4;
  int wy = (wid >> 1) * 32, wx = (wid & 1) * 32;
  f32x4 acc[2][2] = {};
  int srow = tid >> 2, spart = tid & 3;
  const short* Ag = A + (size_t)(m0 + srow) * 256 + spart * 8;
  const short* Wg = W + (size_t)(n0 + srow) * 256 + spart * 8;
  int sidx = srow * 40 + spart * 8;
  for (int k0 = 0; k0 < 256; k0 += 32) {
    __syncthreads();
    *(s16x8*)(As + sidx) = *(const s16x8*)(Ag + k0);
    *(s16x8*)(Bs + sidx) = *(const s16x8*)(Wg + k0);
    __syncthreads();
    s16x8 a0 = *(const s16x8*)(As + (wy + ln15) * 40 + slot * 8);
    s16x8 a1 = *(const s16x8*)(As + (wy + 16 + ln15) * 40 + slot * 8);
    s16x8 b0 = *(const s16x8*)(Bs + (wx + ln15) * 40 + slot * 8);
    s16x8 b1 = *(const s16x8*)(Bs + (wx + 16 + ln15) * 40 + slot * 8);
    acc[0][0] = mfma16(a0, b0, acc[0][0]);
    acc[0][1] = mfma16(a0, b1, acc[0][1]);
    acc[1][0] = mfma16(a1, b0, acc[1][0]);
    acc[1][1] = mfma16(a1, b1, acc[1][1]);
  }
  #pragma unroll
  for (int mf = 0; mf < 2; ++mf)
    #pragma unroll
    for (int nf = 0; nf < 2; ++nf) {
      f32x4 c = acc[mf][nf];
      int gc = n0 + wx + nf * 16 + ln15;
      #pragma unroll
      for (int r = 0; r < 4; ++r) {
        int gr = m0 + wy + mf * 16 + slot * 4 + r;
        int b = gr >= 3136;
        int q = gr - b * 3136;
        if (gc < 256) {
          int w = q % 56;
          float v = (c[r] + PRW[((size_t)(b * 56 + w)) * 256 + gc] + bqr[gc]) * SCALV;
          QR[(size_t)gr * 256 + gc] = v;
        } else if (gc < 512) {
          int jl = gc - 256;
          int h = q / 56;
          float v = (c[r] + PCW[((size_t)(b * 56 + h)) * 256 + jl] + bqc[jl]) * SCALV;
          QC[(size_t)gr * 256 + jl] = v;
        } else {
          int jl = gc - 512;
          int n = jl >> 5, d = jl & 31;
          int h = q / 56, w = q - h * 56;
          float v = c[r] + bv[jl];
          Vt[((size_t)((b * 8 + n) * 32 + d)) * 3584 + h * 64 + w] = (short)f2bfu(v);
        }
      }
    }
}

// 5) Scores + softmax (fp32, unchanged)
__global__ __launch_bounds__(256) void k_scores(
    const float* __restrict__ QR, const float* __restrict__ QC,
    const float* __restrict__ KR, const float* __restrict__ KC,
    const unsigned char* __restrict__ pm,
    float* __restrict__ AWR, float* __restrict__ AWC) {
  __shared__ float Ks[56][33];
  int tid = threadIdx.x;
  int n = blockIdx.y & 7;
  int isCol = blockIdx.y >> 3;
  int b = blockIdx.z;
  const float* Kg = isCol ? KC : KR;
  for (int l = tid; l < 56 * 32; l += 256) {
    int w = l >> 5, d = l & 31;
    Ks[w][d] = Kg[((size_t)(b * 56 + w) << 8) + (n << 5) + d];
  }
  __syncthreads();
  int wave = tid >> 6, ln = tid & 63;
  int q = blockIdx.x * 4 + wave;
  const float* Qg = (isCol ? QC : QR) + ((size_t)(b * 3136 + q) << 8) + (n << 5);
  float sc = -INFINITY;
  if (ln < 56) {
    float s = 0.f;
    #pragma unroll
    for (int d4 = 0; d4 < 8; ++d4) {
      float4 qv = *(const float4*)(Qg + d4 * 4);
      s += qv.x * Ks[ln][d4 * 4 + 0] + qv.y * Ks[ln][d4 * 4 + 1]
         + qv.z * Ks[ln][d4 * 4 + 2] + qv.w * Ks[ln][d4 * 4 + 3];
    }
    bool msk = isCol ? (pm[(size_t)b * 3136 + ln * 56] != 0)
                     : (pm[(size_t)b * 3136 + ln] != 0);
    if (msk) s = -3.402823466e38f;
    sc = s;
  }
  float mx = sc;
  for (int o = 32; o; o >>= 1) mx = fmaxf(mx, __shfl_xor(mx, o));
  float e = (ln < 56) ? __expf(sc - mx) : 0.f;
  float ss = e;
  for (int o = 32; o; o >>= 1) ss += __shfl_xor(ss, o);
  float aw = e / ss;
  if (ln < 56) {
    float* AW = isCol ? AWC : AWR;
    AW[((size_t)(b * 8 + n) * 3136 + q) * 56 + ln] = aw;
  }
}

// 6) Attention recombination via MFMA.
//    out[q,d] = sum_h sum_w ac[q,h]*ar[q,w]*V[h,w,d]; K-space = h*64+w (w padded to 64)
__global__ __launch_bounds__(256) void k_attn_mfma(
    const float* __restrict__ AWR, const float* __restrict__ AWC,
    const short* __restrict__ Vt, short* __restrict__ ATTb) {
  __shared__ float Ac[64][57];
  __shared__ __align__(16) short Vs[8 * 2304];  // 8 h-slabs of [32 d][72]
  int tid = threadIdx.x;
  int q0 = blockIdx.x * 64;
  int n = blockIdx.y, b = blockIdx.z;
  size_t awbase = ((size_t)((b * 8 + n) * 3136) + q0) * 56;
  for (int l = tid; l < 64 * 56; l += 256) {
    int q = l / 56, hh = l - q * 56;
    Ac[q][hh] = AWC[awbase + (size_t)q * 56 + hh];
  }
  int wid = tid >> 6, lane = tid & 63;
  int ln15 = lane & 15, slot = lane >> 4;
  int qb = wid * 16;
  const float* arp = AWR + awbase + (size_t)(qb + ln15) * 56;
  float arA[8], arB[8];
  {
    float4 t0 = *(const float4*)(arp + slot * 8);
    float4 t1 = *(const float4*)(arp + slot * 8 + 4);
    arA[0] = t0.x; arA[1] = t0.y; arA[2] = t0.z; arA[3] = t0.w;
    arA[4] = t1.x; arA[5] = t1.y; arA[6] = t1.z; arA[7] = t1.w;
    if (slot < 3) {
      float4 u0 = *(const float4*)(arp + 32 + slot * 8);
      float4 u1 = *(const float4*)(arp + 36 + slot * 8);
      arB[0] = u0.x; arB[1] = u0.y; arB[2] = u0.z; arB[3] = u0.w;
      arB[4] = u1.x; arB[5] = u1.y; arB[6] = u1.z; arB[7] = u1.w;
    } else {
      #pragma unroll
      for (int j = 0; j < 8; ++j) arB[j] = 0.f;
    }
  }
  const short* Vg = Vt + (size_t)((b * 8 + n) * 32) * 3584;
  f32x4 acc0 = {0.f, 0.f, 0.f, 0.f}, acc1 = {0.f, 0.f, 0.f, 0.f};
  int sd = tid >> 3, spart = tid & 7;
  const short* vsrc = Vg + (size_t)sd * 3584 + spart * 8;
  for (int hc = 0; hc < 7; ++hc) {
    __syncthreads();
    #pragma unroll
    for (int hh = 0; hh < 8; ++hh)
      *(s16x8*)(Vs + hh * 2304 + sd * 72 + spart * 8) =
          *(const s16x8*)(vsrc + (size_t)(hc * 8 + hh) * 64);
    __syncthreads();
    #pragma unroll
    for (int hh = 0; hh < 8; ++hh) {
      float ac = Ac[qb + ln15][hc * 8 + hh];
      s16x8 a0, a1;
      #pragma unroll
      for (int j = 0; j < 8; ++j) a0[j] = (short)f2bfu(ac * arA[j]);
      #pragma unroll
      for (int j = 0; j < 8; ++j) a1[j] = (short)f2bfu(ac * arB[j]);
      const short* vb = Vs + hh * 2304;
      s16x8 b00 = *(const s16x8*)(vb + ln15 * 72 + slot * 8);
      s16x8 b01 = *(const s16x8*)(vb + (16 + ln15) * 72 + slot * 8);
      s16x8 b10 = *(const s16x8*)(vb + ln15 * 72 + 32 + slot * 8);
      s16x8 b11 = *(const s16x8*)(vb + (16 + ln15) * 72 + 32 + slot * 8);
      acc0 = mfma16(a0, b00, acc0);
      acc1 = mfma16(a0, b01, acc1);
      acc0 = mfma16(a1, b10, acc0);
      acc1 = mfma16(a1, b11, acc1);
    }
  }
  size_t obase = ((size_t)(b * 3136 + q0 + qb + slot * 4)) * 256 + n * 32;
  #pragma unroll
  for (int r = 0; r < 4; ++r) {
    ATTb[obase + (size_t)r * 256 + ln15] = (short)f2bfu(acc0[r]);
    ATTb[obase + (size_t)r * 256 + 16 + ln15] = (short)f2bfu(acc1[r]);
  }
}

// 7) Generic bf16 MFMA GEMM: Out(M,N) = A(M,K) @ W(N,K)^T + bias
//    EPI 0: fp32 out.  EPI 1: relu -> bf16 out.
template<int EPI>
__global__ __launch_bounds__(256) void k_gemm_mfma(
    const short* __restrict__ A, const short* __restrict__ W,
    const float* __restrict__ bias, float* __restrict__ outF,
    short* __restrict__ outB, int K, int N) {
  __shared__ __align__(16) short As[2560];
  __shared__ __align__(16) short Bs[2560];
  int tid = threadIdx.x;
  int m0 = blockIdx.x * 64, n0 = blockIdx.y * 64;
  int wid = tid >> 6, lane = tid & 63;
  int ln15 = lane & 15, slot = lane >> 4;
  int wy = (wid >> 1) * 32, wx = (wid & 1) * 32;
  f32x4 acc[2][2] = {};
  int srow = tid >> 2, spart = tid & 3;
  const short* Ag = A + (size_t)(m0 + srow) * K + spart * 8;
  const short* Wg = W + (size_t)(n0 + srow) * K + spart * 8;
  int sidx = srow * 40 + spart * 8;
  for (int k0 = 0; k0 < K; k0 += 32) {
    __syncthreads();
    *(s16x8*)(As + sidx) = *(const s16x8*)(Ag + k0);
    *(s16x8*)(Bs + sidx) = *(const s16x8*)(Wg + k0);
    __syncthreads();
    s16x8 a0 = *(const s16x8*)(As + (wy + ln15) * 40 + slot * 8);
    s16x8 a1 = *(const s16x8*)(As + (wy + 16 + ln15) * 40 + slot * 8);
    s16x8 b0 = *(const s16x8*)(Bs + (wx + ln15) * 40 + slot * 8);
    s16x8 b1 = *(const s16x8*)(Bs + (wx + 16 + ln15) * 40 + slot * 8);
    acc[0][0] = mfma16(a0, b0, acc[0][0]);
    acc[0][1] = mfma16(a0, b1, acc[0][1]);
    acc[1][0] = mfma16(a1, b0, acc[1][0]);
    acc[1][1] = mfma16(a1, b1, acc[1][1]);
  }
  #pragma unroll
  for (int mf = 0; mf < 2; ++mf)
    #pragma unroll
    for (int nf = 0; nf < 2; ++nf) {
      f32x4 c = acc[mf][nf];
      int gc = n0 + wx + nf * 16 + ln15;
      float bs = bias[gc];
      #pragma unroll
      for (int r = 0; r < 4; ++r) {
        int gr = m0 + wy + mf * 16 + slot * 4 + r;
        float v = c[r] + bs;
        if (EPI == 0) outF[(size_t)gr * N + gc] = v;
        else          outB[(size_t)gr * N + gc] = (short)f2bfu(fmaxf(v, 0.f));
      }
    }
}

// 8) LN1: XN1 = LayerNorm(Y + X) -> fp32 + bf16
__global__ __launch_bounds__(256) void k_ln1(
    const float* __restrict__ Y, const float* __restrict__ X,
    const float* __restrict__ g, const float* __restrict__ bb,
    float* __restrict__ XN1f, short* __restrict__ XN1b) {
  int tid = threadIdx.x;
  int row = blockIdx.x * 4 + (tid >> 6);
  int ln = tid & 63;
  size_t base = (size_t)row * 256 + ln * 4;
  float4 y = *(const float4*)(Y + base);
  float4 x = *(const float4*)(X + base);
  float v0 = y.x + x.x, v1 = y.y + x.y, v2 = y.z + x.z, v3 = y.w + x.w;
  float s = v0 + v1 + v2 + v3;
  float s2 = v0 * v0 + v1 * v1 + v2 * v2 + v3 * v3;
  for (int o = 32; o; o >>= 1) { s += __shfl_xor(s, o); s2 += __shfl_xor(s2, o); }
  float m = s * (1.f / 256.f);
  float inv = rsqrtf(fmaxf(s2 * (1.f / 256.f) - m * m, 0.f) + EPSV);
  float4 gg = *(const float4*)(g + ln * 4);
  float4 bv = *(const float4*)(bb + ln * 4);
  float4 o4;
  o4.x = (v0 - m) * inv * gg.x + bv.x;
  o4.y = (v1 - m) * inv * gg.y + bv.y;
  o4.z = (v2 - m) * inv * gg.z + bv.z;
  o4.w = (v3 - m) * inv * gg.w + bv.w;
  *(float4*)(XN1f + base) = o4;
  uint2 pk;
  pk.x = (unsigned)f2bfu(o4.x) | ((unsigned)f2bfu(o4.y) << 16);
  pk.y = (unsigned)f2bfu(o4.z) | ((unsigned)f2bfu(o4.w) << 16);
  *(uint2*)(XN1b + base) = pk;
}

// 9) LN2 + transposed store to (B,C,H,W)
__global__ __launch_bounds__(256) void k_ln2t(
    const float* __restrict__ Y2, const float* __restrict__ XN1,
    const float* __restrict__ g, const float* __restrict__ bb,
    float* __restrict__ out) {
  __shared__ float VL[16][257];
  int tid = threadIdx.x;
  int r0 = blockIdx.x * 16;
  for (int l = tid; l < 16 * 256; l += 256) {
    int r = l >> 8, c = l & 255;
    VL[r][c] = Y2[(size_t)(r0 + r) * 256 + c] + XN1[(size_t)(r0 + r) * 256 + c];
  }
  __syncthreads();
  int wv = tid >> 6, ln = tid & 63;
  for (int rr = wv; rr < 16; rr += 4) {
    float s = 0.f, s2 = 0.f;
    float vv[4];
    #pragma unroll
    for (int i = 0; i < 4; ++i) {
      float v = VL[rr][ln * 4 + i];
      vv[i] = v; s += v; s2 += v * v;
    }
    for (int o = 32; o; o >>= 1) { s += __shfl_xor(s, o); s2 += __shfl_xor(s2, o); }
    float m = s * (1.f / 256.f);
    float inv = rsqrtf(fmaxf(s2 * (1.f / 256.f) - m * m, 0.f) + EPSV);
    #pragma unroll
    for (int i = 0; i < 4; ++i) {
      int c = ln * 4 + i;
      VL[rr][c] = (vv[i] - m) * inv * g[c] + bb[c];
    }
  }
  __syncthreads();
  int b = r0 / 3136;
  int hw0 = r0 % 3136;
  int r = tid & 15, cg = tid >> 4;
  for (int it = 0; it < 16; ++it) {
    int c = it * 16 + cg;
    out[(size_t)(b * 256 + c) * 3136 + hw0 + r] = VL[r][c];
  }
}

// ---------------------------------------------------------------------------
extern "C" void kernel_launch(void* const* d_in, const int* in_sizes, int n_in,
                              void* d_out, int out_size, void* d_ws, size_t ws_size,
                              hipStream_t stream) {
  const float* src = (const float*)d_in[0];
  const unsigned char* pmask = (const unsigned char*)d_in[1];
  const float* per = (const float*)d_in[2];
  const float* pec = (const float*)d_in[3];
  const float* wqr = (const float*)d_in[4];
  const float* bqr = (const float*)d_in[5];
  const float* wqc = (const float*)d_in[6];
  const float* bqc = (const float*)d_in[7];
  const float* wkr = (const float*)d_in[8];
  const float* bkr = (const float*)d_in[9];
  const float* wkc = (const float*)d_in[10];
  const float* bkc = (const float*)d_in[11];
  const float* wv  = (const float*)d_in[12];
  const float* bv  = (const float*)d_in[13];
  const float* wo  = (const float*)d_in[14];
  const float* bo  = (const float*)d_in[15];
  const float* n1g = (const float*)d_in[16];
  const float* n1b = (const float*)d_in[17];
  const float* l1w = (const float*)d_in[18];
  const float* l1b = (const float*)d_in[19];
  const float* l2w = (const float*)d_in[20];
  const float* l2b = (const float*)d_in[21];
  const float* n2g = (const float*)d_in[22];
  const float* n2b = (const float*)d_in[23];

  float* ws = (float*)d_ws;
  float* X    = ws + 0;
  short* Xb   = (short*)(ws + 1605632);
  float* QR   = ws + 2408448;
  float* QC   = ws + 4014080;
  short* Vt   = (short*)(ws + 5619712);
  float* AWR  = ws + 6537216;
  float* AWC  = ws + 9347072;
  short* ATTb = (short*)(ws + 12156928);
  short* FFb  = (short*)(ws + 12959744);
  float* Y    = ws + 16171008;     // also Y2
  float* XN1f = ws + 17776640;
  short* XN1b = (short*)(ws + 19382272);
  float* MH   = ws + 20185088;
  float* MW   = ws + 20213760;
  float* PRW  = ws + 20242432;
  float* PCW  = ws + 20271104;
  float* KR   = ws + 20299776;
  float* KC   = ws + 20328448;
  short* Wcat = (short*)(ws + 20357120);
  short* wob  = (short*)(ws + 20455424);
  short* l1wb = (short*)(ws + 20488192);
  short* l2wb = (short*)(ws + 20619264);
  float* out = (float*)d_out;

  k_pack<<<dim3(256, 4), 256, 0, stream>>>(wqr, wqc, wv, wo, l1w, l2w,
                                           Wcat, wob, l1wb, l2wb);
  k_transpose<<<dim3(98, 8, 2), dim3(32, 8), 0, stream>>>(src, X, Xb);
  k_means<<<dim3(256, 2), 64, 0, stream>>>(src, MH, MW);
  k_smallproj<<<448, 256, 0, stream>>>(per, pec, MH, MW, wqr, wqc, wkr, wkc,
                                       bkr, bkc, PRW, PCW, KR, KC);
  k_projmfma<<<dim3(98, 12), 256, 0, stream>>>(Xb, Wcat, bqr, bqc, bv,
                                               PRW, PCW, QR, QC, Vt);
  k_scores<<<dim3(784, 16, 2), 256, 0, stream>>>(QR, QC, KR, KC, pmask, AWR, AWC);
  k_attn_mfma<<<dim3(49, 8, 2), 256, 0, stream>>>(AWR, AWC, Vt, ATTb);
  k_gemm_mfma<0><<<dim3(98, 4), 256, 0, stream>>>(ATTb, wob, bo, Y, nullptr, 256, 256);
  k_ln1<<<1568, 256, 0, stream>>>(Y, X, n1g, n1b, XN1f, XN1b);
  k_gemm_mfma<1><<<dim3(98, 16), 256, 0, stream>>>(XN1b, l1wb, l1b, nullptr, FFb, 256, 1024);
  k_gemm_mfma<0><<<dim3(98, 4), 256, 0, stream>>>(FFb, l2wb, l2b, Y, nullptr, 1024, 256);
  k_ln2t<<<392, 256, 0, stream>>>(Y, XN1f, n2g, n2b, out);
}

// Round 3
// 275.629 us; speedup vs baseline: 2.6510x; 1.1194x over previous
//
#include <hip/hip_runtime.h>
#include <math.h>

#define EPSV 1e-5f
#define SCALV 0.17677669529663687f   // 32^-0.5

typedef __attribute__((ext_vector_type(8))) short s16x8;
typedef __attribute__((ext_vector_type(8))) __bf16 bf8_t;
typedef __attribute__((ext_vector_type(4))) float f32x4;

__device__ inline unsigned short f2bfu(float f) {
  union { float f; unsigned u; } v; v.f = f;
  return (unsigned short)((v.u + 0x7FFFu + ((v.u >> 16) & 1u)) >> 16);
}

__device__ inline f32x4 mfma16(s16x8 a, s16x8 b, f32x4 c) {
  return __builtin_amdgcn_mfma_f32_16x16x32_bf16(
      __builtin_bit_cast(bf8_t, a), __builtin_bit_cast(bf8_t, b), c, 0, 0, 0);
}

__device__ inline void gll16(const void* g, void* l) {
  __builtin_amdgcn_global_load_lds(
      (const __attribute__((address_space(1))) unsigned*)g,
      (__attribute__((address_space(3))) unsigned*)l, 16, 0, 0);
}

// ---------------------------------------------------------------------------
// 1) Transpose src (B,C,HW) -> X (B,HW,C) fp32 + Xb bf16
__global__ __launch_bounds__(256) void k_transpose(const float* __restrict__ src,
                                                   float* __restrict__ X,
                                                   short* __restrict__ Xb) {
  __shared__ float tile[32][33];
  int b = blockIdx.z;
  int hw0 = blockIdx.x * 32, c0 = blockIdx.y * 32;
  int tx = threadIdx.x, ty = threadIdx.y;
  for (int i = ty; i < 32; i += 8)
    tile[i][tx] = src[((size_t)(b * 256 + c0 + i)) * 3136 + hw0 + tx];
  __syncthreads();
  for (int i = ty; i < 32; i += 8) {
    float v = tile[tx][i];
    size_t idx = ((size_t)(b * 3136 + hw0 + i)) * 256 + c0 + tx;
    X[idx] = v;
    Xb[idx] = (short)f2bfu(v);
  }
}

// 2) Mean over h (->MH: B,W,C) and over w (->MW: B,H,C)
__global__ void k_means(const float* __restrict__ src, float* __restrict__ MH, float* __restrict__ MW) {
  int c = blockIdx.x, b = blockIdx.y, t = threadIdx.x;
  if (t >= 56) return;
  const float* p = src + ((size_t)(b * 256 + c)) * 3136;
  float sH = 0.f, sW = 0.f;
  for (int i = 0; i < 56; ++i) {
    sH += p[i * 56 + t];
    sW += p[t * 56 + i];
  }
  MH[((size_t)(b * 56 + t)) * 256 + c] = sH * (1.f / 56.f);
  MW[((size_t)(b * 56 + t)) * 256 + c] = sW * (1.f / 56.f);
}

// 3) Small projections (112 rows each)
__global__ __launch_bounds__(256) void k_smallproj(
    const float* __restrict__ per, const float* __restrict__ pec,
    const float* __restrict__ mh, const float* __restrict__ mw,
    const float* __restrict__ wqr, const float* __restrict__ wqc,
    const float* __restrict__ wkr, const float* __restrict__ wkc,
    const float* __restrict__ bkr, const float* __restrict__ bkc,
    float* __restrict__ PRW, float* __restrict__ PCW,
    float* __restrict__ KR, float* __restrict__ KC) {
  __shared__ __align__(16) float inb[256];
  int s = blockIdx.x / 112;
  int r = blockIdx.x % 112;
  int j = threadIdx.x;
  const float* i0; const float* i1 = nullptr; const float* W;
  const float* bias = nullptr; float* out;
  if (s == 0)      { i0 = per; W = wqr; out = PRW; }
  else if (s == 1) { i0 = pec; W = wqc; out = PCW; }
  else if (s == 2) { i0 = per; i1 = mh; W = wkr; bias = bkr; out = KR; }
  else             { i0 = pec; i1 = mw; W = wkc; bias = bkc; out = KC; }
  float v = i0[(size_t)r * 256 + j];
  if (i1) v += i1[(size_t)r * 256 + j];
  inb[j] = v;
  __syncthreads();
  const float* wrow = W + (size_t)j * 256;
  float acc = 0.f;
  #pragma unroll
  for (int c4 = 0; c4 < 64; ++c4) {
    float4 iv = *(const float4*)(&inb[c4 * 4]);
    float4 wv = *(const float4*)(wrow + c4 * 4);
    acc += iv.x * wv.x + iv.y * wv.y + iv.z * wv.z + iv.w * wv.w;
  }
  if (bias) acc += bias[j];
  out[(size_t)r * 256 + j] = acc;
}

// 3b) Pack weights to bf16
__global__ __launch_bounds__(256) void k_pack(
    const float* __restrict__ wqr, const float* __restrict__ wqc, const float* __restrict__ wv,
    const float* __restrict__ wo, const float* __restrict__ l1w, const float* __restrict__ l2w,
    short* __restrict__ Wcat, short* __restrict__ wob,
    short* __restrict__ l1b, short* __restrict__ l2b) {
  int seg = blockIdx.y;
  int e = (blockIdx.x * 256 + threadIdx.x) * 4;
  int cnt = (seg == 0) ? 196608 : (seg == 1) ? 65536 : 262144;
  if (e >= cnt) return;
  const float* sp;
  short* dp;
  if (seg == 0) {
    dp = Wcat + e;
    sp = (e < 65536) ? wqr + e : (e < 131072) ? wqc + (e - 65536) : wv + (e - 131072);
  } else if (seg == 1) { dp = wob + e; sp = wo + e; }
  else if (seg == 2)   { dp = l1b + e; sp = l1w + e; }
  else                 { dp = l2b + e; sp = l2w + e; }
  float4 v = *(const float4*)sp;
  uint2 p;
  p.x = (unsigned)f2bfu(v.x) | ((unsigned)f2bfu(v.y) << 16);
  p.y = (unsigned)f2bfu(v.z) | ((unsigned)f2bfu(v.w) << 16);
  *(uint2*)dp = p;
}

// ---------------------------------------------------------------------------
// 4) 128x128-tile MFMA GEMM core (m97 structure: global_load_lds + XOR swizzle)
//    Staging: lane l, inst i -> row = 32*wid + 8*i + (l>>3), swizzled source col.
#define GEMM128_CORE(Aptr, Wptr, Kdim)                                          \
  __shared__ __align__(16) short As[8192];                                      \
  __shared__ __align__(16) short Bs[8192];                                      \
  int tid = threadIdx.x;                                                        \
  int wid = tid >> 6, lane = tid & 63;                                          \
  int ln15 = lane & 15, slot = lane >> 4;                                       \
  int m0 = blockIdx.x * 128, n0 = blockIdx.y * 128;                             \
  int srow = (wid << 5) + (lane >> 3);                                          \
  int scb = (((lane & 7) ^ ((lane >> 3) & 7)) << 4);                            \
  const char* Ag = (const char*)(Aptr + (size_t)(m0 + srow) * Kdim) + scb;      \
  const char* Wg = (const char*)(Wptr + (size_t)(n0 + srow) * Kdim) + scb;      \
  char* Al = (char*)As + (wid << 12) + lane * 16;                               \
  char* Bl = (char*)Bs + (wid << 12) + lane * 16;                               \
  int wm0 = ((wid >> 1) << 6), wn0 = ((wid & 1) << 6);                          \
  f32x4 acc[4][4] = {};                                                         \
  for (int k0 = 0; k0 < Kdim; k0 += 64) {                                       \
    __syncthreads();                                                            \
    size_t koff = (size_t)k0 * 2;                                               \
    _Pragma("unroll")                                                           \
    for (int i = 0; i < 4; ++i) {                                               \
      gll16(Ag + (size_t)(i * 8) * Kdim * 2 + koff, Al + i * 1024);             \
      gll16(Wg + (size_t)(i * 8) * Kdim * 2 + koff, Bl + i * 1024);             \
    }                                                                           \
    __syncthreads();                                                            \
    _Pragma("unroll")                                                           \
    for (int kc = 0; kc < 2; ++kc) {                                            \
      s16x8 af[4], bf[4];                                                       \
      int rcb = (kc * 64 + slot * 16) ^ ((ln15 & 7) << 4);                      \
      _Pragma("unroll")                                                         \
      for (int mf = 0; mf < 4; ++mf)                                            \
        af[mf] = *(const s16x8*)((const char*)As + (wm0 + (mf << 4) + ln15) * 128 + rcb); \
      _Pragma("unroll")                                                         \
      for (int nf = 0; nf < 4; ++nf)                                            \
        bf[nf] = *(const s16x8*)((const char*)Bs + (wn0 + (nf << 4) + ln15) * 128 + rcb); \
      _Pragma("unroll")                                                         \
      for (int mf = 0; mf < 4; ++mf)                                            \
        _Pragma("unroll")                                                       \
        for (int nf = 0; nf < 4; ++nf)                                          \
          acc[mf][nf] = mfma16(af[mf], bf[nf], acc[mf][nf]);                    \
    }                                                                           \
  }

// Generic: Out = A @ W^T + bias ; EPI 0: fp32 out, EPI 1: relu->bf16 out
template<int EPI>
__global__ __launch_bounds__(256) void k_gemm128(
    const short* __restrict__ A, const short* __restrict__ W,
    const float* __restrict__ bias, float* __restrict__ outF,
    short* __restrict__ outB, int K, int N) {
  GEMM128_CORE(A, W, K)
  #pragma unroll
  for (int mf = 0; mf < 4; ++mf)
    #pragma unroll
    for (int nf = 0; nf < 4; ++nf) {
      int gc = n0 + wn0 + (nf << 4) + ln15;
      float bs = bias[gc];
      #pragma unroll
      for (int r = 0; r < 4; ++r) {
        int gr = m0 + wm0 + (mf << 4) + (slot << 2) + r;
        float v = acc[mf][nf][r] + bs;
        if (EPI == 0) outF[(size_t)gr * N + gc] = v;
        else          outB[(size_t)gr * N + gc] = (short)f2bfu(fmaxf(v, 0.f));
      }
    }
}

// Fused projection: Xb(6272,256) @ Wcat(768,256)^T, segmented epilogue
__global__ __launch_bounds__(256) void k_proj128(
    const short* __restrict__ A, const short* __restrict__ W,
    const float* __restrict__ bqr, const float* __restrict__ bqc, const float* __restrict__ bv,
    const float* __restrict__ PRW, const float* __restrict__ PCW,
    float* __restrict__ QR, float* __restrict__ QC, short* __restrict__ Vt) {
  GEMM128_CORE(A, W, 256)
  int s = n0 >> 8;   // 0: QR, 1: QC, 2: V
  #pragma unroll
  for (int mf = 0; mf < 4; ++mf)
    #pragma unroll
    for (int nf = 0; nf < 4; ++nf) {
      f32x4 c = acc[mf][nf];
      int gc = n0 + wn0 + (nf << 4) + ln15;
      int jl = gc & 255;
      #pragma unroll
      for (int r = 0; r < 4; ++r) {
        int gr = m0 + wm0 + (mf << 4) + (slot << 2) + r;
        int bb = gr >= 3136;
        int q = gr - bb * 3136;
        if (s == 0) {
          int w = q % 56;
          QR[(size_t)gr * 256 + jl] =
              (c[r] + PRW[((size_t)(bb * 56 + w)) * 256 + jl] + bqr[jl]) * SCALV;
        } else if (s == 1) {
          int h = q / 56;
          QC[(size_t)gr * 256 + jl] =
              (c[r] + PCW[((size_t)(bb * 56 + h)) * 256 + jl] + bqc[jl]) * SCALV;
        } else {
          int nn = jl >> 5, d = jl & 31;
          int h = q / 56, w = q - h * 56;
          Vt[((size_t)((bb * 8 + nn) * 32 + d)) * 3584 + h * 64 + w] =
              (short)f2bfu(c[r] + bv[jl]);
        }
      }
    }
}

// 5) Scores + softmax: 32 q per block (4 waves x 8), K staged once
__global__ __launch_bounds__(256) void k_scores2(
    const float* __restrict__ QR, const float* __restrict__ QC,
    const float* __restrict__ KR, const float* __restrict__ KC,
    const unsigned char* __restrict__ pm,
    float* __restrict__ AWR, float* __restrict__ AWC) {
  __shared__ float Ks[56][33];
  int tid = threadIdx.x;
  int n = blockIdx.y & 7;
  int isCol = blockIdx.y >> 3;
  int b = blockIdx.z;
  const float* Kg = isCol ? KC : KR;
  for (int l = tid; l < 56 * 32; l += 256) {
    int w = l >> 5, d = l & 31;
    Ks[w][d] = Kg[((size_t)(b * 56 + w) << 8) + (n << 5) + d];
  }
  __syncthreads();
  int wave = tid >> 6, ln = tid & 63;
  const float* Qbase = (isCol ? QC : QR);
  float* AW = isCol ? AWC : AWR;
  bool msk = (ln < 56) && (isCol ? (pm[(size_t)b * 3136 + ln * 56] != 0)
                                 : (pm[(size_t)b * 3136 + ln] != 0));
  for (int it = 0; it < 8; ++it) {
    int q = blockIdx.x * 32 + wave * 8 + it;
    const float* Qg = Qbase + ((size_t)(b * 3136 + q) << 8) + (n << 5);
    float sc = -INFINITY;
    if (ln < 56) {
      float s = 0.f;
      #pragma unroll
      for (int d4 = 0; d4 < 8; ++d4) {
        float4 qv = *(const float4*)(Qg + d4 * 4);
        s += qv.x * Ks[ln][d4 * 4 + 0] + qv.y * Ks[ln][d4 * 4 + 1]
           + qv.z * Ks[ln][d4 * 4 + 2] + qv.w * Ks[ln][d4 * 4 + 3];
      }
      if (msk) s = -3.402823466e38f;
      sc = s;
    }
    float mx = sc;
    for (int o = 32; o; o >>= 1) mx = fmaxf(mx, __shfl_xor(mx, o));
    float e = (ln < 56) ? __expf(sc - mx) : 0.f;
    float ss = e;
    for (int o = 32; o; o >>= 1) ss += __shfl_xor(ss, o);
    float aw = e / ss;
    if (ln < 56)
      AW[((size_t)(b * 8 + n) * 3136 + q) * 56 + ln] = aw;
  }
}

// 6) Attention recombination: TMP_h = V_h(d x w) @ ar^T(w x q) via MFMA,
//    out[d][q] += ac[q][h] * TMP_h (fp32 fmac). 128 q/block, 32 q/wave.
__global__ __launch_bounds__(256, 4) void k_attn2(
    const float* __restrict__ AWR, const float* __restrict__ AWC,
    const short* __restrict__ Vt, short* __restrict__ ATTb) {
  __shared__ __align__(16) short Vs[4 * 2304];     // [hh][32 d][72 w]
  __shared__ __align__(16) short Acs[128 * 57];    // bf16 ac
  int tid = threadIdx.x;
  int wid = tid >> 6, lane = tid & 63;
  int ln15 = lane & 15, slot = lane >> 4;
  int q0 = blockIdx.x * 128;
  int n = blockIdx.y, b = blockIdx.z;
  int bn = b * 8 + n;
  size_t awbase = (size_t)bn * 3136 * 56;
  // stage Ac (bf16)
  for (int l = tid; l < 128 * 56; l += 256) {
    int q = l / 56, h = l - (l / 56) * 56;
    int qc = q0 + q; if (qc > 3135) qc = 3135;
    Acs[q * 57 + h] = (short)f2bfu(AWC[awbase + (size_t)qc * 56 + h]);
  }
  // prepack ar B-fragments (col = q = ln15, k = w)
  s16x8 bfr[2][2];
  #pragma unroll
  for (int qf = 0; qf < 2; ++qf) {
    int qc = q0 + wid * 32 + qf * 16 + ln15; if (qc > 3135) qc = 3135;
    const float* arp = AWR + awbase + (size_t)qc * 56;
    #pragma unroll
    for (int kc = 0; kc < 2; ++kc) {
      if (kc == 1 && slot == 3) {
        s16x8 z = {};
        bfr[qf][1] = z;
      } else {
        float4 t0 = *(const float4*)(arp + kc * 32 + slot * 8);
        float4 t1 = *(const float4*)(arp + kc * 32 + slot * 8 + 4);
        s16x8 f;
        f[0] = (short)f2bfu(t0.x); f[1] = (short)f2bfu(t0.y);
        f[2] = (short)f2bfu(t0.z); f[3] = (short)f2bfu(t0.w);
        f[4] = (short)f2bfu(t1.x); f[5] = (short)f2bfu(t1.y);
        f[6] = (short)f2bfu(t1.z); f[7] = (short)f2bfu(t1.w);
        bfr[qf][kc] = f;
      }
    }
  }
  const short* Vg = Vt + (size_t)bn * 32 * 3584;
  int sd = (tid >> 3) & 31, swp = tid & 7;
  const short* vsrc = Vg + (size_t)sd * 3584 + swp * 8;
  short* vdst = Vs + sd * 72 + swp * 8;
  s16x8 pre[4];
  #pragma unroll
  for (int i = 0; i < 4; ++i)
    pre[i] = *(const s16x8*)(vsrc + (size_t)i * 64);
  #pragma unroll
  for (int i = 0; i < 4; ++i)
    *(s16x8*)(vdst + i * 2304) = pre[i];
  __syncthreads();

  f32x4 oacc[2][2] = {};
  for (int hc = 0; hc < 14; ++hc) {
    if (hc < 13) {
      #pragma unroll
      for (int i = 0; i < 4; ++i)
        pre[i] = *(const s16x8*)(vsrc + (size_t)((hc + 1) * 4 + i) * 64);
    }
    #pragma unroll
    for (int hh = 0; hh < 4; ++hh) {
      int h = hc * 4 + hh;
      s16x8 af[2][2];
      #pragma unroll
      for (int df = 0; df < 2; ++df)
        #pragma unroll
        for (int kc = 0; kc < 2; ++kc)
          af[df][kc] = *(const s16x8*)(Vs + hh * 2304 + (df * 16 + ln15) * 72 + kc * 32 + slot * 8);
      #pragma unroll
      for (int qf = 0; qf < 2; ++qf) {
        float acv = __uint_as_float(
            ((unsigned)(unsigned short)Acs[(wid * 32 + qf * 16 + ln15) * 57 + h]) << 16);
        #pragma unroll
        for (int df = 0; df < 2; ++df) {
          f32x4 tmp = {0.f, 0.f, 0.f, 0.f};
          tmp = mfma16(af[df][0], bfr[qf][0], tmp);
          tmp = mfma16(af[df][1], bfr[qf][1], tmp);
          oacc[df][qf][0] += acv * tmp[0];
          oacc[df][qf][1] += acv * tmp[1];
          oacc[df][qf][2] += acv * tmp[2];
          oacc[df][qf][3] += acv * tmp[3];
        }
      }
    }
    if (hc < 13) {
      __syncthreads();
      #pragma unroll
      for (int i = 0; i < 4; ++i)
        *(s16x8*)(vdst + i * 2304) = pre[i];
      __syncthreads();
    }
  }
  // transpose out via LDS (reuse Vs), then coalesced bf16 store
  __syncthreads();
  #pragma unroll
  for (int df = 0; df < 2; ++df)
    #pragma unroll
    for (int qf = 0; qf < 2; ++qf) {
      int qi = wid * 32 + qf * 16 + ln15;
      short4 pk;
      pk.x = (short)f2bfu(oacc[df][qf][0]);
      pk.y = (short)f2bfu(oacc[df][qf][1]);
      pk.z = (short)f2bfu(oacc[df][qf][2]);
      pk.w = (short)f2bfu(oacc[df][qf][3]);
      *(short4*)(Vs + qi * 36 + df * 16 + slot * 4) = pk;
    }
  __syncthreads();
  int q = tid >> 1, half = tid & 1;
  int qg = q0 + q;
  if (qg < 3136) {
    s16x8 v = *(const s16x8*)(Vs + q * 36 + half * 16);
    *(s16x8*)(ATTb + ((size_t)(b * 3136 + qg)) * 256 + n * 32 + half * 16) = v;
  }
}

// 8) LN1: XN1 = LayerNorm(Y + X) -> fp32 + bf16
__global__ __launch_bounds__(256) void k_ln1(
    const float* __restrict__ Y, const float* __restrict__ X,
    const float* __restrict__ g, const float* __restrict__ bb,
    float* __restrict__ XN1f, short* __restrict__ XN1b) {
  int tid = threadIdx.x;
  int row = blockIdx.x * 4 + (tid >> 6);
  int ln = tid & 63;
  size_t base = (size_t)row * 256 + ln * 4;
  float4 y = *(const float4*)(Y + base);
  float4 x = *(const float4*)(X + base);
  float v0 = y.x + x.x, v1 = y.y + x.y, v2 = y.z + x.z, v3 = y.w + x.w;
  float s = v0 + v1 + v2 + v3;
  float s2 = v0 * v0 + v1 * v1 + v2 * v2 + v3 * v3;
  for (int o = 32; o; o >>= 1) { s += __shfl_xor(s, o); s2 += __shfl_xor(s2, o); }
  float m = s * (1.f / 256.f);
  float inv = rsqrtf(fmaxf(s2 * (1.f / 256.f) - m * m, 0.f) + EPSV);
  float4 gg = *(const float4*)(g + ln * 4);
  float4 bv = *(const float4*)(bb + ln * 4);
  float4 o4;
  o4.x = (v0 - m) * inv * gg.x + bv.x;
  o4.y = (v1 - m) * inv * gg.y + bv.y;
  o4.z = (v2 - m) * inv * gg.z + bv.z;
  o4.w = (v3 - m) * inv * gg.w + bv.w;
  *(float4*)(XN1f + base) = o4;
  uint2 pk;
  pk.x = (unsigned)f2bfu(o4.x) | ((unsigned)f2bfu(o4.y) << 16);
  pk.y = (unsigned)f2bfu(o4.z) | ((unsigned)f2bfu(o4.w) << 16);
  *(uint2*)(XN1b + base) = pk;
}

// 9) LN2 + transposed store to (B,C,H,W)
__global__ __launch_bounds__(256) void k_ln2t(
    const float* __restrict__ Y2, const float* __restrict__ XN1,
    const float* __restrict__ g, const float* __restrict__ bb,
    float* __restrict__ out) {
  __shared__ float VL[16][257];
  int tid = threadIdx.x;
  int r0 = blockIdx.x * 16;
  for (int l = tid; l < 16 * 256; l += 256) {
    int r = l >> 8, c = l & 255;
    VL[r][c] = Y2[(size_t)(r0 + r) * 256 + c] + XN1[(size_t)(r0 + r) * 256 + c];
  }
  __syncthreads();
  int wv = tid >> 6, ln = tid & 63;
  for (int rr = wv; rr < 16; rr += 4) {
    float s = 0.f, s2 = 0.f;
    float vv[4];
    #pragma unroll
    for (int i = 0; i < 4; ++i) {
      float v = VL[rr][ln * 4 + i];
      vv[i] = v; s += v; s2 += v * v;
    }
    for (int o = 32; o; o >>= 1) { s += __shfl_xor(s, o); s2 += __shfl_xor(s2, o); }
    float m = s * (1.f / 256.f);
    float inv = rsqrtf(fmaxf(s2 * (1.f / 256.f) - m * m, 0.f) + EPSV);
    #pragma unroll
    for (int i = 0; i < 4; ++i) {
      int c = ln * 4 + i;
      VL[rr][c] = (vv[i] - m) * inv * g[c] + bb[c];
    }
  }
  __syncthreads();
  int b = r0 / 3136;
  int hw0 = r0 % 3136;
  int r = tid & 15, cg = tid >> 4;
  for (int it = 0; it < 16; ++it) {
    int c = it * 16 + cg;
    out[(size_t)(b * 256 + c) * 3136 + hw0 + r] = VL[r][c];
  }
}

// ---------------------------------------------------------------------------
extern "C" void kernel_launch(void* const* d_in, const int* in_sizes, int n_in,
                              void* d_out, int out_size, void* d_ws, size_t ws_size,
                              hipStream_t stream) {
  const float* src = (const float*)d_in[0];
  const unsigned char* pmask = (const unsigned char*)d_in[1];
  const float* per = (const float*)d_in[2];
  const float* pec = (const float*)d_in[3];
  const float* wqr = (const float*)d_in[4];
  const float* bqr = (const float*)d_in[5];
  const float* wqc = (const float*)d_in[6];
  const float* bqc = (const float*)d_in[7];
  const float* wkr = (const float*)d_in[8];
  const float* bkr = (const float*)d_in[9];
  const float* wkc = (const float*)d_in[10];
  const float* bkc = (const float*)d_in[11];
  const float* wv  = (const float*)d_in[12];
  const float* bv  = (const float*)d_in[13];
  const float* wo  = (const float*)d_in[14];
  const float* bo  = (const float*)d_in[15];
  const float* n1g = (const float*)d_in[16];
  const float* n1b = (const float*)d_in[17];
  const float* l1w = (const float*)d_in[18];
  const float* l1b = (const float*)d_in[19];
  const float* l2w = (const float*)d_in[20];
  const float* l2b = (const float*)d_in[21];
  const float* n2g = (const float*)d_in[22];
  const float* n2b = (const float*)d_in[23];

  float* ws = (float*)d_ws;
  float* X    = ws + 0;
  short* Xb   = (short*)(ws + 1605632);
  float* QR   = ws + 2408448;
  float* QC   = ws + 4014080;
  short* Vt   = (short*)(ws + 5619712);
  float* AWR  = ws + 6537216;
  float* AWC  = ws + 9347072;
  short* ATTb = (short*)(ws + 12156928);
  short* FFb  = (short*)(ws + 12959744);
  float* Y    = ws + 16171008;     // also Y2
  float* XN1f = ws + 17776640;
  short* XN1b = (short*)(ws + 19382272);
  float* MH   = ws + 20185088;
  float* MW   = ws + 20213760;
  float* PRW  = ws + 20242432;
  float* PCW  = ws + 20271104;
  float* KR   = ws + 20299776;
  float* KC   = ws + 20328448;
  short* Wcat = (short*)(ws + 20357120);
  short* wob  = (short*)(ws + 20455424);
  short* l1wb = (short*)(ws + 20488192);
  short* l2wb = (short*)(ws + 20619264);
  float* out = (float*)d_out;

  k_pack<<<dim3(256, 4), 256, 0, stream>>>(wqr, wqc, wv, wo, l1w, l2w,
                                           Wcat, wob, l1wb, l2wb);
  k_transpose<<<dim3(98, 8, 2), dim3(32, 8), 0, stream>>>(src, X, Xb);
  k_means<<<dim3(256, 2), 64, 0, stream>>>(src, MH, MW);
  k_smallproj<<<448, 256, 0, stream>>>(per, pec, MH, MW, wqr, wqc, wkr, wkc,
                                       bkr, bkc, PRW, PCW, KR, KC);
  k_proj128<<<dim3(49, 6), 256, 0, stream>>>(Xb, Wcat, bqr, bqc, bv,
                                             PRW, PCW, QR, QC, Vt);
  k_scores2<<<dim3(98, 16, 2), 256, 0, stream>>>(QR, QC, KR, KC, pmask, AWR, AWC);
  k_attn2<<<dim3(25, 8, 2), 256, 0, stream>>>(AWR, AWC, Vt, ATTb);
  k_gemm128<0><<<dim3(49, 2), 256, 0, stream>>>(ATTb, wob, bo, Y, nullptr, 256, 256);
  k_ln1<<<1568, 256, 0, stream>>>(Y, X, n1g, n1b, XN1f, XN1b);
  k_gemm128<1><<<dim3(49, 8), 256, 0, stream>>>(XN1b, l1wb, l1b, nullptr, FFb, 256, 1024);
  k_gemm128<0><<<dim3(49, 2), 256, 0, stream>>>(FFb, l2wb, l2b, Y, nullptr, 1024, 256);
  k_ln2t<<<392, 256, 0, stream>>>(Y, XN1f, n2g, n2b, out);
}

// Round 4
// 255.777 us; speedup vs baseline: 2.8568x; 1.0776x over previous
//
#include <hip/hip_runtime.h>
#include <math.h>

#define EPSV 1e-5f
#define SCALV 0.17677669529663687f   // 32^-0.5

typedef __attribute__((ext_vector_type(8))) short s16x8;
typedef __attribute__((ext_vector_type(8))) __bf16 bf8_t;
typedef __attribute__((ext_vector_type(4))) float f32x4;

__device__ inline unsigned short f2bfu(float f) {
  union { float f; unsigned u; } v; v.f = f;
  return (unsigned short)((v.u + 0x7FFFu + ((v.u >> 16) & 1u)) >> 16);
}

__device__ inline f32x4 mfma16(s16x8 a, s16x8 b, f32x4 c) {
  return __builtin_amdgcn_mfma_f32_16x16x32_bf16(
      __builtin_bit_cast(bf8_t, a), __builtin_bit_cast(bf8_t, b), c, 0, 0, 0);
}

__device__ inline void gll16(const void* g, const void* l) {
  __builtin_amdgcn_global_load_lds(
      (const __attribute__((address_space(1))) unsigned*)g,
      (__attribute__((address_space(3))) unsigned*)l, 16, 0, 0);
}

// ---------------------------------------------------------------------------
// 1) Transpose src (B,C,HW) -> X (B,HW,C) fp32 + Xb bf16
__global__ __launch_bounds__(256) void k_transpose(const float* __restrict__ src,
                                                   float* __restrict__ X,
                                                   short* __restrict__ Xb) {
  __shared__ float tile[32][33];
  int b = blockIdx.z;
  int hw0 = blockIdx.x * 32, c0 = blockIdx.y * 32;
  int tx = threadIdx.x, ty = threadIdx.y;
  for (int i = ty; i < 32; i += 8)
    tile[i][tx] = src[((size_t)(b * 256 + c0 + i)) * 3136 + hw0 + tx];
  __syncthreads();
  for (int i = ty; i < 32; i += 8) {
    float v = tile[tx][i];
    size_t idx = ((size_t)(b * 3136 + hw0 + i)) * 256 + c0 + tx;
    X[idx] = v;
    Xb[idx] = (short)f2bfu(v);
  }
}

// 2) Mean over h (->MH: B,W,C) and over w (->MW: B,H,C)
__global__ void k_means(const float* __restrict__ src, float* __restrict__ MH, float* __restrict__ MW) {
  int c = blockIdx.x, b = blockIdx.y, t = threadIdx.x;
  if (t >= 56) return;
  const float* p = src + ((size_t)(b * 256 + c)) * 3136;
  float sH = 0.f, sW = 0.f;
  for (int i = 0; i < 56; ++i) {
    sH += p[i * 56 + t];
    sW += p[t * 56 + i];
  }
  MH[((size_t)(b * 56 + t)) * 256 + c] = sH * (1.f / 56.f);
  MW[((size_t)(b * 56 + t)) * 256 + c] = sW * (1.f / 56.f);
}

// 3) Small projections (112 rows each)
__global__ __launch_bounds__(256) void k_smallproj(
    const float* __restrict__ per, const float* __restrict__ pec,
    const float* __restrict__ mh, const float* __restrict__ mw,
    const float* __restrict__ wqr, const float* __restrict__ wqc,
    const float* __restrict__ wkr, const float* __restrict__ wkc,
    const float* __restrict__ bkr, const float* __restrict__ bkc,
    float* __restrict__ PRW, float* __restrict__ PCW,
    float* __restrict__ KR, float* __restrict__ KC) {
  __shared__ __align__(16) float inb[256];
  int s = blockIdx.x / 112;
  int r = blockIdx.x % 112;
  int j = threadIdx.x;
  const float* i0; const float* i1 = nullptr; const float* W;
  const float* bias = nullptr; float* out;
  if (s == 0)      { i0 = per; W = wqr; out = PRW; }
  else if (s == 1) { i0 = pec; W = wqc; out = PCW; }
  else if (s == 2) { i0 = per; i1 = mh; W = wkr; bias = bkr; out = KR; }
  else             { i0 = pec; i1 = mw; W = wkc; bias = bkc; out = KC; }
  float v = i0[(size_t)r * 256 + j];
  if (i1) v += i1[(size_t)r * 256 + j];
  inb[j] = v;
  __syncthreads();
  const float* wrow = W + (size_t)j * 256;
  float acc = 0.f;
  #pragma unroll
  for (int c4 = 0; c4 < 64; ++c4) {
    float4 iv = *(const float4*)(&inb[c4 * 4]);
    float4 wv = *(const float4*)(wrow + c4 * 4);
    acc += iv.x * wv.x + iv.y * wv.y + iv.z * wv.z + iv.w * wv.w;
  }
  if (bias) acc += bias[j];
  out[(size_t)r * 256 + j] = acc;
}

// 3b) Pack weights to bf16
__global__ __launch_bounds__(256) void k_pack(
    const float* __restrict__ wqr, const float* __restrict__ wqc, const float* __restrict__ wv,
    const float* __restrict__ wo, const float* __restrict__ l1w, const float* __restrict__ l2w,
    short* __restrict__ Wcat, short* __restrict__ wob,
    short* __restrict__ l1b, short* __restrict__ l2b) {
  int seg = blockIdx.y;
  int e = (blockIdx.x * 256 + threadIdx.x) * 4;
  int cnt = (seg == 0) ? 196608 : (seg == 1) ? 65536 : 262144;
  if (e >= cnt) return;
  const float* sp;
  short* dp;
  if (seg == 0) {
    dp = Wcat + e;
    sp = (e < 65536) ? wqr + e : (e < 131072) ? wqc + (e - 65536) : wv + (e - 131072);
  } else if (seg == 1) { dp = wob + e; sp = wo + e; }
  else if (seg == 2)   { dp = l1b + e; sp = l1w + e; }
  else                 { dp = l2b + e; sp = l2w + e; }
  float4 v = *(const float4*)sp;
  uint2 p;
  p.x = (unsigned)f2bfu(v.x) | ((unsigned)f2bfu(v.y) << 16);
  p.y = (unsigned)f2bfu(v.z) | ((unsigned)f2bfu(v.w) << 16);
  *(uint2*)dp = p;
}

// ---------------------------------------------------------------------------
// 4) 64x64-tile 2-phase pipelined MFMA GEMM core.
//    gll16 with WAVE-UNIFORM LDS base (readfirstlane); XOR-swizzled source,
//    matching swizzled ds_read (bank-conflict-free, 128B rows).
#define GEMM64_CORE(Aptr, Wptr, Kdim)                                           \
  __shared__ __align__(16) short Ls[2][2][4096];                                \
  int tid = threadIdx.x;                                                        \
  int wid = tid >> 6, lane = tid & 63;                                          \
  int ln15 = lane & 15, slot = lane >> 4;                                       \
  int m0 = blockIdx.x * 64, n0 = blockIdx.y * 64;                               \
  int l8 = lane >> 3, c8 = lane & 7;                                            \
  int csw = ((c8 ^ l8) << 4);                                                   \
  int K2 = (Kdim) * 2;                                                          \
  const char* Ag = (const char*)(Aptr) + (size_t)(m0 + wid * 16 + l8) * K2 + csw; \
  const char* Wg = (const char*)(Wptr) + (size_t)(n0 + wid * 16 + l8) * K2 + csw; \
  int u0 = __builtin_amdgcn_readfirstlane(wid * 2048);                          \
  int wm0 = (wid >> 1) << 5, wn0 = (wid & 1) << 5;                              \
  int xr = ln15 & 7;                                                            \
  f32x4 acc[2][2] = {};                                                         \
  int nt = (Kdim) >> 6;                                                         \
  {                                                                             \
    char* bA = (char*)&Ls[0][0][0];                                             \
    char* bB = (char*)&Ls[0][1][0];                                             \
    gll16(Ag, bA + u0);                                                         \
    gll16(Ag + (size_t)8 * K2, bA + u0 + 1024);                                 \
    gll16(Wg, bB + u0);                                                         \
    gll16(Wg + (size_t)8 * K2, bB + u0 + 1024);                                 \
  }                                                                             \
  __syncthreads();                                                              \
  for (int t = 0; t < nt; ++t) {                                                \
    int bf = t & 1;                                                             \
    if (t + 1 < nt) {                                                           \
      size_t ko = (size_t)(t + 1) * 128;                                        \
      char* bA = (char*)&Ls[bf ^ 1][0][0];                                      \
      char* bB = (char*)&Ls[bf ^ 1][1][0];                                      \
      gll16(Ag + ko, bA + u0);                                                  \
      gll16(Ag + ko + (size_t)8 * K2, bA + u0 + 1024);                          \
      gll16(Wg + ko, bB + u0);                                                  \
      gll16(Wg + ko + (size_t)8 * K2, bB + u0 + 1024);                          \
    }                                                                           \
    const char* LA = (const char*)&Ls[bf][0][0];                                \
    const char* LB = (const char*)&Ls[bf][1][0];                                \
    _Pragma("unroll")                                                           \
    for (int kc = 0; kc < 2; ++kc) {                                            \
      s16x8 af[2], bv2[2];                                                      \
      _Pragma("unroll")                                                         \
      for (int mf = 0; mf < 2; ++mf)                                            \
        af[mf] = *(const s16x8*)(LA + (wm0 + mf * 16 + ln15) * 128              \
                                  + (((kc * 4 + slot) ^ xr) << 4));             \
      _Pragma("unroll")                                                         \
      for (int nf = 0; nf < 2; ++nf)                                            \
        bv2[nf] = *(const s16x8*)(LB + (wn0 + nf * 16 + ln15) * 128             \
                                   + (((kc * 4 + slot) ^ xr) << 4));            \
      _Pragma("unroll")                                                         \
      for (int mf = 0; mf < 2; ++mf)                                            \
        _Pragma("unroll")                                                       \
        for (int nf = 0; nf < 2; ++nf)                                          \
          acc[mf][nf] = mfma16(af[mf], bv2[nf], acc[mf][nf]);                   \
    }                                                                           \
    __syncthreads();                                                            \
  }

// Generic: Out = A @ W^T + bias ; EPI 0: fp32 out, EPI 1: relu->bf16 out
template<int EPI>
__global__ __launch_bounds__(256) void k_gemm64p(
    const short* __restrict__ A, const short* __restrict__ W,
    const float* __restrict__ bias, float* __restrict__ outF,
    short* __restrict__ outB, int K, int N) {
  GEMM64_CORE(A, W, K)
  #pragma unroll
  for (int mf = 0; mf < 2; ++mf)
    #pragma unroll
    for (int nf = 0; nf < 2; ++nf) {
      int gc = n0 + wn0 + (nf << 4) + ln15;
      float bs = bias[gc];
      #pragma unroll
      for (int r = 0; r < 4; ++r) {
        int gr = m0 + wm0 + (mf << 4) + (slot << 2) + r;
        float v = acc[mf][nf][r] + bs;
        if (EPI == 0) outF[(size_t)gr * N + gc] = v;
        else          outB[(size_t)gr * N + gc] = (short)f2bfu(fmaxf(v, 0.f));
      }
    }
}

// Fused projection: Xb(6272,256) @ Wcat(768,256)^T, segmented epilogue
__global__ __launch_bounds__(256) void k_proj64p(
    const short* __restrict__ A, const short* __restrict__ W,
    const float* __restrict__ bqr, const float* __restrict__ bqc, const float* __restrict__ bv,
    const float* __restrict__ PRW, const float* __restrict__ PCW,
    float* __restrict__ QR, float* __restrict__ QC, short* __restrict__ Vt) {
  GEMM64_CORE(A, W, 256)
  int s = n0 >> 8;   // 0: QR, 1: QC, 2: V
  #pragma unroll
  for (int mf = 0; mf < 2; ++mf)
    #pragma unroll
    for (int nf = 0; nf < 2; ++nf) {
      f32x4 c = acc[mf][nf];
      int gc = n0 + wn0 + (nf << 4) + ln15;
      int jl = gc & 255;
      #pragma unroll
      for (int r = 0; r < 4; ++r) {
        int gr = m0 + wm0 + (mf << 4) + (slot << 2) + r;
        int bb = gr >= 3136;
        int q = gr - bb * 3136;
        if (s == 0) {
          int w = q % 56;
          QR[(size_t)gr * 256 + jl] =
              (c[r] + PRW[((size_t)(bb * 56 + w)) * 256 + jl] + bqr[jl]) * SCALV;
        } else if (s == 1) {
          int h = q / 56;
          QC[(size_t)gr * 256 + jl] =
              (c[r] + PCW[((size_t)(bb * 56 + h)) * 256 + jl] + bqc[jl]) * SCALV;
        } else {
          int nn = jl >> 5, d = jl & 31;
          int h = q / 56, w = q - h * 56;
          Vt[((size_t)((bb * 8 + nn) * 32 + d)) * 3584 + h * 64 + w] =
              (short)f2bfu(c[r] + bv[jl]);
        }
      }
    }
}

// 5) Scores + softmax: 32 q per block (4 waves x 8), K staged once
__global__ __launch_bounds__(256) void k_scores2(
    const float* __restrict__ QR, const float* __restrict__ QC,
    const float* __restrict__ KR, const float* __restrict__ KC,
    const unsigned char* __restrict__ pm,
    float* __restrict__ AWR, float* __restrict__ AWC) {
  __shared__ float Ks[56][33];
  int tid = threadIdx.x;
  int n = blockIdx.y & 7;
  int isCol = blockIdx.y >> 3;
  int b = blockIdx.z;
  const float* Kg = isCol ? KC : KR;
  for (int l = tid; l < 56 * 32; l += 256) {
    int w = l >> 5, d = l & 31;
    Ks[w][d] = Kg[((size_t)(b * 56 + w) << 8) + (n << 5) + d];
  }
  __syncthreads();
  int wave = tid >> 6, ln = tid & 63;
  const float* Qbase = (isCol ? QC : QR);
  float* AW = isCol ? AWC : AWR;
  bool msk = (ln < 56) && (isCol ? (pm[(size_t)b * 3136 + ln * 56] != 0)
                                 : (pm[(size_t)b * 3136 + ln] != 0));
  for (int it = 0; it < 8; ++it) {
    int q = blockIdx.x * 32 + wave * 8 + it;
    const float* Qg = Qbase + ((size_t)(b * 3136 + q) << 8) + (n << 5);
    float sc = -INFINITY;
    if (ln < 56) {
      float s = 0.f;
      #pragma unroll
      for (int d4 = 0; d4 < 8; ++d4) {
        float4 qv = *(const float4*)(Qg + d4 * 4);
        s += qv.x * Ks[ln][d4 * 4 + 0] + qv.y * Ks[ln][d4 * 4 + 1]
           + qv.z * Ks[ln][d4 * 4 + 2] + qv.w * Ks[ln][d4 * 4 + 3];
      }
      if (msk) s = -3.402823466e38f;
      sc = s;
    }
    float mx = sc;
    for (int o = 32; o; o >>= 1) mx = fmaxf(mx, __shfl_xor(mx, o));
    float e = (ln < 56) ? __expf(sc - mx) : 0.f;
    float ss = e;
    for (int o = 32; o; o >>= 1) ss += __shfl_xor(ss, o);
    float aw = e / ss;
    if (ln < 56)
      AW[((size_t)(b * 8 + n) * 3136 + q) * 56 + ln] = aw;
  }
}

// 6) Attention recombination: TMP_h = V_h(d x w) @ ar^T(w x q) via MFMA,
//    out[d][q] += ac[q][h] * TMP_h (fp32 fmac). 128 q/block, 32 q/wave.
__global__ __launch_bounds__(256, 4) void k_attn2(
    const float* __restrict__ AWR, const float* __restrict__ AWC,
    const short* __restrict__ Vt, short* __restrict__ ATTb) {
  __shared__ __align__(16) short Vs[4 * 2304];     // [hh][32 d][72 w]
  __shared__ __align__(16) short Acs[128 * 57];    // bf16 ac
  int tid = threadIdx.x;
  int wid = tid >> 6, lane = tid & 63;
  int ln15 = lane & 15, slot = lane >> 4;
  int q0 = blockIdx.x * 128;
  int n = blockIdx.y, b = blockIdx.z;
  int bn = b * 8 + n;
  size_t awbase = (size_t)bn * 3136 * 56;
  // stage Ac (bf16)
  for (int l = tid; l < 128 * 56; l += 256) {
    int q = l / 56, h = l - (l / 56) * 56;
    int qc = q0 + q; if (qc > 3135) qc = 3135;
    Acs[q * 57 + h] = (short)f2bfu(AWC[awbase + (size_t)qc * 56 + h]);
  }
  // prepack ar B-fragments (col = q = ln15, k = w)
  s16x8 bfr[2][2];
  #pragma unroll
  for (int qf = 0; qf < 2; ++qf) {
    int qc = q0 + wid * 32 + qf * 16 + ln15; if (qc > 3135) qc = 3135;
    const float* arp = AWR + awbase + (size_t)qc * 56;
    #pragma unroll
    for (int kc = 0; kc < 2; ++kc) {
      if (kc == 1 && slot == 3) {
        s16x8 z = {};
        bfr[qf][1] = z;
      } else {
        float4 t0 = *(const float4*)(arp + kc * 32 + slot * 8);
        float4 t1 = *(const float4*)(arp + kc * 32 + slot * 8 + 4);
        s16x8 f;
        f[0] = (short)f2bfu(t0.x); f[1] = (short)f2bfu(t0.y);
        f[2] = (short)f2bfu(t0.z); f[3] = (short)f2bfu(t0.w);
        f[4] = (short)f2bfu(t1.x); f[5] = (short)f2bfu(t1.y);
        f[6] = (short)f2bfu(t1.z); f[7] = (short)f2bfu(t1.w);
        bfr[qf][kc] = f;
      }
    }
  }
  const short* Vg = Vt + (size_t)bn * 32 * 3584;
  int sd = (tid >> 3) & 31, swp = tid & 7;
  const short* vsrc = Vg + (size_t)sd * 3584 + swp * 8;
  short* vdst = Vs + sd * 72 + swp * 8;
  s16x8 pre[4];
  #pragma unroll
  for (int i = 0; i < 4; ++i)
    pre[i] = *(const s16x8*)(vsrc + (size_t)i * 64);
  #pragma unroll
  for (int i = 0; i < 4; ++i)
    *(s16x8*)(vdst + i * 2304) = pre[i];
  __syncthreads();

  f32x4 oacc[2][2] = {};
  for (int hc = 0; hc < 14; ++hc) {
    if (hc < 13) {
      #pragma unroll
      for (int i = 0; i < 4; ++i)
        pre[i] = *(const s16x8*)(vsrc + (size_t)((hc + 1) * 4 + i) * 64);
    }
    #pragma unroll
    for (int hh = 0; hh < 4; ++hh) {
      int h = hc * 4 + hh;
      s16x8 af[2][2];
      #pragma unroll
      for (int df = 0; df < 2; ++df)
        #pragma unroll
        for (int kc = 0; kc < 2; ++kc)
          af[df][kc] = *(const s16x8*)(Vs + hh * 2304 + (df * 16 + ln15) * 72 + kc * 32 + slot * 8);
      #pragma unroll
      for (int qf = 0; qf < 2; ++qf) {
        float acv = __uint_as_float(
            ((unsigned)(unsigned short)Acs[(wid * 32 + qf * 16 + ln15) * 57 + h]) << 16);
        #pragma unroll
        for (int df = 0; df < 2; ++df) {
          f32x4 tmp = {0.f, 0.f, 0.f, 0.f};
          tmp = mfma16(af[df][0], bfr[qf][0], tmp);
          tmp = mfma16(af[df][1], bfr[qf][1], tmp);
          oacc[df][qf][0] += acv * tmp[0];
          oacc[df][qf][1] += acv * tmp[1];
          oacc[df][qf][2] += acv * tmp[2];
          oacc[df][qf][3] += acv * tmp[3];
        }
      }
    }
    if (hc < 13) {
      __syncthreads();
      #pragma unroll
      for (int i = 0; i < 4; ++i)
        *(s16x8*)(vdst + i * 2304) = pre[i];
      __syncthreads();
    }
  }
  // transpose out via LDS (reuse Vs), then coalesced bf16 store
  __syncthreads();
  #pragma unroll
  for (int df = 0; df < 2; ++df)
    #pragma unroll
    for (int qf = 0; qf < 2; ++qf) {
      int qi = wid * 32 + qf * 16 + ln15;
      short4 pk;
      pk.x = (short)f2bfu(oacc[df][qf][0]);
      pk.y = (short)f2bfu(oacc[df][qf][1]);
      pk.z = (short)f2bfu(oacc[df][qf][2]);
      pk.w = (short)f2bfu(oacc[df][qf][3]);
      *(short4*)(Vs + qi * 36 + df * 16 + slot * 4) = pk;
    }
  __syncthreads();
  int q = tid >> 1, half = tid & 1;
  int qg = q0 + q;
  if (qg < 3136) {
    s16x8 v = *(const s16x8*)(Vs + q * 36 + half * 16);
    *(s16x8*)(ATTb + ((size_t)(b * 3136 + qg)) * 256 + n * 32 + half * 16) = v;
  }
}

// 8) LN1: XN1 = LayerNorm(Y + X) -> fp32 + bf16
__global__ __launch_bounds__(256) void k_ln1(
    const float* __restrict__ Y, const float* __restrict__ X,
    const float* __restrict__ g, const float* __restrict__ bb,
    float* __restrict__ XN1f, short* __restrict__ XN1b) {
  int tid = threadIdx.x;
  int row = blockIdx.x * 4 + (tid >> 6);
  int ln = tid & 63;
  size_t base = (size_t)row * 256 + ln * 4;
  float4 y = *(const float4*)(Y + base);
  float4 x = *(const float4*)(X + base);
  float v0 = y.x + x.x, v1 = y.y + x.y, v2 = y.z + x.z, v3 = y.w + x.w;
  float s = v0 + v1 + v2 + v3;
  float s2 = v0 * v0 + v1 * v1 + v2 * v2 + v3 * v3;
  for (int o = 32; o; o >>= 1) { s += __shfl_xor(s, o); s2 += __shfl_xor(s2, o); }
  float m = s * (1.f / 256.f);
  float inv = rsqrtf(fmaxf(s2 * (1.f / 256.f) - m * m, 0.f) + EPSV);
  float4 gg = *(const float4*)(g + ln * 4);
  float4 bv = *(const float4*)(bb + ln * 4);
  float4 o4;
  o4.x = (v0 - m) * inv * gg.x + bv.x;
  o4.y = (v1 - m) * inv * gg.y + bv.y;
  o4.z = (v2 - m) * inv * gg.z + bv.z;
  o4.w = (v3 - m) * inv * gg.w + bv.w;
  *(float4*)(XN1f + base) = o4;
  uint2 pk;
  pk.x = (unsigned)f2bfu(o4.x) | ((unsigned)f2bfu(o4.y) << 16);
  pk.y = (unsigned)f2bfu(o4.z) | ((unsigned)f2bfu(o4.w) << 16);
  *(uint2*)(XN1b + base) = pk;
}

// 9) LN2 + transposed store to (B,C,H,W)
__global__ __launch_bounds__(256) void k_ln2t(
    const float* __restrict__ Y2, const float* __restrict__ XN1,
    const float* __restrict__ g, const float* __restrict__ bb,
    float* __restrict__ out) {
  __shared__ float VL[16][257];
  int tid = threadIdx.x;
  int r0 = blockIdx.x * 16;
  for (int l = tid; l < 16 * 256; l += 256) {
    int r = l >> 8, c = l & 255;
    VL[r][c] = Y2[(size_t)(r0 + r) * 256 + c] + XN1[(size_t)(r0 + r) * 256 + c];
  }
  __syncthreads();
  int wv = tid >> 6, ln = tid & 63;
  for (int rr = wv; rr < 16; rr += 4) {
    float s = 0.f, s2 = 0.f;
    float vv[4];
    #pragma unroll
    for (int i = 0; i < 4; ++i) {
      float v = VL[rr][ln * 4 + i];
      vv[i] = v; s += v; s2 += v * v;
    }
    for (int o = 32; o; o >>= 1) { s += __shfl_xor(s, o); s2 += __shfl_xor(s2, o); }
    float m = s * (1.f / 256.f);
    float inv = rsqrtf(fmaxf(s2 * (1.f / 256.f) - m * m, 0.f) + EPSV);
    #pragma unroll
    for (int i = 0; i < 4; ++i) {
      int c = ln * 4 + i;
      VL[rr][c] = (vv[i] - m) * inv * g[c] + bb[c];
    }
  }
  __syncthreads();
  int b = r0 / 3136;
  int hw0 = r0 % 3136;
  int r = tid & 15, cg = tid >> 4;
  for (int it = 0; it < 16; ++it) {
    int c = it * 16 + cg;
    out[(size_t)(b * 256 + c) * 3136 + hw0 + r] = VL[r][c];
  }
}

// ---------------------------------------------------------------------------
extern "C" void kernel_launch(void* const* d_in, const int* in_sizes, int n_in,
                              void* d_out, int out_size, void* d_ws, size_t ws_size,
                              hipStream_t stream) {
  const float* src = (const float*)d_in[0];
  const unsigned char* pmask = (const unsigned char*)d_in[1];
  const float* per = (const float*)d_in[2];
  const float* pec = (const float*)d_in[3];
  const float* wqr = (const float*)d_in[4];
  const float* bqr = (const float*)d_in[5];
  const float* wqc = (const float*)d_in[6];
  const float* bqc = (const float*)d_in[7];
  const float* wkr = (const float*)d_in[8];
  const float* bkr = (const float*)d_in[9];
  const float* wkc = (const float*)d_in[10];
  const float* bkc = (const float*)d_in[11];
  const float* wv  = (const float*)d_in[12];
  const float* bv  = (const float*)d_in[13];
  const float* wo  = (const float*)d_in[14];
  const float* bo  = (const float*)d_in[15];
  const float* n1g = (const float*)d_in[16];
  const float* n1b = (const float*)d_in[17];
  const float* l1w = (const float*)d_in[18];
  const float* l1b = (const float*)d_in[19];
  const float* l2w = (const float*)d_in[20];
  const float* l2b = (const float*)d_in[21];
  const float* n2g = (const float*)d_in[22];
  const float* n2b = (const float*)d_in[23];

  float* ws = (float*)d_ws;
  float* X    = ws + 0;
  short* Xb   = (short*)(ws + 1605632);
  float* QR   = ws + 2408448;
  float* QC   = ws + 4014080;
  short* Vt   = (short*)(ws + 5619712);
  float* AWR  = ws + 6537216;
  float* AWC  = ws + 9347072;
  short* ATTb = (short*)(ws + 12156928);
  short* FFb  = (short*)(ws + 12959744);
  float* Y    = ws + 16171008;     // also Y2
  float* XN1f = ws + 17776640;
  short* XN1b = (short*)(ws + 19382272);
  float* MH   = ws + 20185088;
  float* MW   = ws + 20213760;
  float* PRW  = ws + 20242432;
  float* PCW  = ws + 20271104;
  float* KR   = ws + 20299776;
  float* KC   = ws + 20328448;
  short* Wcat = (short*)(ws + 20357120);
  short* wob  = (short*)(ws + 20455424);
  short* l1wb = (short*)(ws + 20488192);
  short* l2wb = (short*)(ws + 20619264);
  float* out = (float*)d_out;

  k_pack<<<dim3(256, 4), 256, 0, stream>>>(wqr, wqc, wv, wo, l1w, l2w,
                                           Wcat, wob, l1wb, l2wb);
  k_transpose<<<dim3(98, 8, 2), dim3(32, 8), 0, stream>>>(src, X, Xb);
  k_means<<<dim3(256, 2), 64, 0, stream>>>(src, MH, MW);
  k_smallproj<<<448, 256, 0, stream>>>(per, pec, MH, MW, wqr, wqc, wkr, wkc,
                                       bkr, bkc, PRW, PCW, KR, KC);
  k_proj64p<<<dim3(98, 12), 256, 0, stream>>>(Xb, Wcat, bqr, bqc, bv,
                                              PRW, PCW, QR, QC, Vt);
  k_scores2<<<dim3(98, 16, 2), 256, 0, stream>>>(QR, QC, KR, KC, pmask, AWR, AWC);
  k_attn2<<<dim3(25, 8, 2), 256, 0, stream>>>(AWR, AWC, Vt, ATTb);
  k_gemm64p<0><<<dim3(98, 4), 256, 0, stream>>>(ATTb, wob, bo, Y, nullptr, 256, 256);
  k_ln1<<<1568, 256, 0, stream>>>(Y, X, n1g, n1b, XN1f, XN1b);
  k_gemm64p<1><<<dim3(98, 16), 256, 0, stream>>>(XN1b, l1wb, l1b, nullptr, FFb, 256, 1024);
  k_gemm64p<0><<<dim3(98, 4), 256, 0, stream>>>(FFb, l2wb, l2b, Y, nullptr, 1024, 256);
  k_ln2t<<<392, 256, 0, stream>>>(Y, XN1f, n2g, n2b, out);
}